// Round 1
// baseline (565.418 us; speedup 1.0000x reference)
//
#include <hip/hip_runtime.h>
#include <math.h>

#define NN 50000
#define NE 800000
#define DM 128
#define NH 8
#define FF 512

// 16 FMAs of a 4x4 register tile
#define FMA16(acc, a0, a1, a2, a3, b)                                                     \
    acc[0][0] += a0 * b.x; acc[0][1] += a0 * b.y; acc[0][2] += a0 * b.z; acc[0][3] += a0 * b.w; \
    acc[1][0] += a1 * b.x; acc[1][1] += a1 * b.y; acc[1][2] += a1 * b.z; acc[1][3] += a1 * b.w; \
    acc[2][0] += a2 * b.x; acc[2][1] += a2 * b.y; acc[2][2] += a2 * b.z; acc[2][3] += a2 * b.w; \
    acc[3][0] += a3 * b.x; acc[3][1] += a3 * b.y; acc[3][2] += a3 * b.z; acc[3][3] += a3 * b.w;

// ---------------------------------------------------------------------------
// rowptr[n] = lower_bound(row, n); row is sorted ascending.
__global__ void k_rowptr(const int* __restrict__ row, int* __restrict__ rowptr) {
    int n = blockIdx.x * blockDim.x + threadIdx.x;
    if (n > NN) return;
    int lo = 0, hi = NE;
    while (lo < hi) {
        int mid = (lo + hi) >> 1;
        if (row[mid] < n) lo = mid + 1; else hi = mid;
    }
    rowptr[n] = lo;
}

// ---------------------------------------------------------------------------
// Load 32 rows x 128 cols of src into LDS tile (stride 132), zero-padded OOB.
__device__ __forceinline__ void load_tile32(const float* __restrict__ src, int r0,
                                            float (*tile)[132], int tid) {
    int r = tid >> 3;
    int c = (tid & 7) * 16;
    int gr = r0 + r;
    float4 v0, v1, v2, v3;
    if (gr < NN) {
        const float4* s = (const float4*)(src + (size_t)gr * DM + c);
        v0 = s[0]; v1 = s[1]; v2 = s[2]; v3 = s[3];
    } else {
        v0 = make_float4(0.f, 0.f, 0.f, 0.f);
        v1 = v0; v2 = v0; v3 = v0;
    }
    *(float4*)&tile[r][c + 0]  = v0;
    *(float4*)&tile[r][c + 4]  = v1;
    *(float4*)&tile[r][c + 8]  = v2;
    *(float4*)&tile[r][c + 12] = v3;
}

// ---------------------------------------------------------------------------
// QKV projection: 32 rows/block, 256 threads, 4x4 register tile per thread.
__global__ __launch_bounds__(256) void k_qkv(
    const float* __restrict__ x,
    const float* __restrict__ Wq, const float* __restrict__ bq,
    const float* __restrict__ Wk, const float* __restrict__ bk,
    const float* __restrict__ Wv, const float* __restrict__ bv,
    float* __restrict__ Q, float* __restrict__ K, float* __restrict__ V)
{
    __shared__ float xs[32][132];
    const int tid = threadIdx.x;
    const int r0 = blockIdx.x * 32;
    load_tile32(x, r0, xs, tid);
    __syncthreads();

    const int tx = tid & 31;   // col group: cols tx*4 .. tx*4+3
    const int ty = tid >> 5;   // row group: rows ty*4 .. ty*4+3
    const float* Ws[3] = {Wq, Wk, Wv};
    const float* bs[3] = {bq, bk, bv};
    float* Os[3] = {Q, K, V};

    #pragma unroll
    for (int m = 0; m < 3; ++m) {
        const float* __restrict__ W = Ws[m];
        float acc[4][4] = {};
        #pragma unroll 4
        for (int k = 0; k < DM; ++k) {
            float4 b = *(const float4*)(W + k * DM + tx * 4);
            float a0 = xs[ty * 4 + 0][k];
            float a1 = xs[ty * 4 + 1][k];
            float a2 = xs[ty * 4 + 2][k];
            float a3 = xs[ty * 4 + 3][k];
            FMA16(acc, a0, a1, a2, a3, b);
        }
        float4 bias = *(const float4*)(bs[m] + tx * 4);
        #pragma unroll
        for (int rr = 0; rr < 4; ++rr) {
            int gr = r0 + ty * 4 + rr;
            if (gr < NN) {
                float4 o = make_float4(acc[rr][0] + bias.x, acc[rr][1] + bias.y,
                                       acc[rr][2] + bias.z, acc[rr][3] + bias.w);
                *(float4*)(Os[m] + (size_t)gr * DM + tx * 4) = o;
            }
        }
    }
}

// ---------------------------------------------------------------------------
// Edge scores: one thread per (edge, head).
__global__ __launch_bounds__(256) void k_scores(
    const float* __restrict__ Q, const float* __restrict__ Km,
    const int* __restrict__ row, const int* __restrict__ col,
    const int* __restrict__ db, const float* __restrict__ emb,
    float* __restrict__ scores)
{
    long gid = (long)blockIdx.x * 256 + threadIdx.x;
    if (gid >= (long)NE * NH) return;
    int e = (int)(gid >> 3);
    int h = (int)(gid & 7);
    int r = row[e], c = col[e];
    const float4* q = (const float4*)(Q + (size_t)r * DM + h * 16);
    const float4* k = (const float4*)(Km + (size_t)c * DM + h * 16);
    float s = 0.f;
    #pragma unroll
    for (int i = 0; i < 4; ++i) {
        float4 a = q[i], b = k[i];
        s += a.x * b.x + a.y * b.y + a.z * b.z + a.w * b.w;
    }
    s *= 0.25f;  // 1/sqrt(16)
    s += emb[db[r] * NH + h] + emb[db[c] * NH + h];
    scores[gid] = s;
}

// ---------------------------------------------------------------------------
// Segment softmax over sorted row + weighted aggregation of V[col].
// One 128-thread block per node.
__global__ __launch_bounds__(128) void k_attn(
    const float* __restrict__ scores, const float* __restrict__ V,
    const int* __restrict__ col, const int* __restrict__ rowptr,
    float* __restrict__ agg)
{
    const int n = blockIdx.x;
    const int tid = threadIdx.x;
    const int e0 = rowptr[n], e1 = rowptr[n + 1];

    __shared__ float red[128];
    __shared__ float mh[NH], sh[NH];

    const int h = tid & 7;       // head for reduction phase
    const int s = tid >> 3;      // 16 slots per head

    // max per head
    float m = -INFINITY;
    for (int e = e0 + s; e < e1; e += 16) m = fmaxf(m, scores[(size_t)e * NH + h]);
    red[tid] = m;
    __syncthreads();
    if (tid < NH) {
        float mm = -INFINITY;
        #pragma unroll
        for (int i = 0; i < 16; ++i) mm = fmaxf(mm, red[tid + 8 * i]);
        mh[tid] = mm;
    }
    __syncthreads();

    // sum of exp per head
    float mm = mh[h];
    float sum = 0.f;
    for (int e = e0 + s; e < e1; e += 16) sum += expf(scores[(size_t)e * NH + h] - mm);
    red[tid] = sum;
    __syncthreads();
    if (tid < NH) {
        float ss = 0.f;
        #pragma unroll
        for (int i = 0; i < 16; ++i) ss += red[tid + 8 * i];
        sh[tid] = fmaxf(ss, 1e-12f);
    }
    __syncthreads();

    // aggregation: thread tid handles (h = tid/16, dh = tid%16)
    const int th = tid >> 4;
    const float mb = mh[th];
    const float sb = sh[th];
    float acc = 0.f;
    for (int e = e0; e < e1; ++e) {
        int c = col[e];
        float alpha = expf(scores[(size_t)e * NH + th] - mb) / sb;
        acc += alpha * V[(size_t)c * DM + tid];
    }
    agg[(size_t)n * DM + tid] = acc;
}

// ---------------------------------------------------------------------------
// out = agg@Wo + bo; resid = x + out; h = LN1(resid)
__global__ __launch_bounds__(256) void k_proj_ln1(
    const float* __restrict__ agg, const float* __restrict__ x,
    const float* __restrict__ Wo, const float* __restrict__ bo,
    const float* __restrict__ g, const float* __restrict__ b,
    float* __restrict__ hout)
{
    __shared__ float as_[32][132];
    __shared__ float hs[32][132];
    __shared__ float mu[32], rstd[32];
    const int tid = threadIdx.x;
    const int r0 = blockIdx.x * 32;
    load_tile32(agg, r0, as_, tid);
    __syncthreads();

    const int tx = tid & 31, ty = tid >> 5;
    float acc[4][4] = {};
    #pragma unroll 4
    for (int k = 0; k < DM; ++k) {
        float4 bv = *(const float4*)(Wo + k * DM + tx * 4);
        float a0 = as_[ty * 4 + 0][k];
        float a1 = as_[ty * 4 + 1][k];
        float a2 = as_[ty * 4 + 2][k];
        float a3 = as_[ty * 4 + 3][k];
        FMA16(acc, a0, a1, a2, a3, bv);
    }
    float4 bias = *(const float4*)(bo + tx * 4);
    #pragma unroll
    for (int rr = 0; rr < 4; ++rr) {
        int r = ty * 4 + rr;
        int gr = r0 + r;
        float4 xr = make_float4(0.f, 0.f, 0.f, 0.f);
        if (gr < NN) xr = *(const float4*)(x + (size_t)gr * DM + tx * 4);
        float4 v = make_float4(acc[rr][0] + bias.x + xr.x, acc[rr][1] + bias.y + xr.y,
                               acc[rr][2] + bias.z + xr.z, acc[rr][3] + bias.w + xr.w);
        *(float4*)&hs[r][tx * 4] = v;
    }
    __syncthreads();

    if (tid < 32) {
        float s = 0.f, q = 0.f;
        #pragma unroll 4
        for (int k = 0; k < DM; ++k) { float v = hs[tid][k]; s += v; q += v * v; }
        float m = s * (1.f / DM);
        float var = q * (1.f / DM) - m * m;
        mu[tid] = m;
        rstd[tid] = rsqrtf(var + 1e-5f);
    }
    __syncthreads();

    int r = tid >> 3, c0 = (tid & 7) * 16;
    int gr = r0 + r;
    if (gr < NN) {
        float m = mu[r], rs = rstd[r];
        #pragma unroll
        for (int i = 0; i < 16; ++i) {
            int c = c0 + i;
            hout[(size_t)gr * DM + c] = (hs[r][c] - m) * rs * g[c] + b[c];
        }
    }
}

// ---------------------------------------------------------------------------
// ffo = gelu(h@W1+b1); y = ffo@W2+b2; out = LN2(h + y)
// 512 FF cols processed in 4 chunks of 128 with immediate W2 partial-accum.
__global__ __launch_bounds__(256) void k_ffn_ln2(
    const float* __restrict__ h,
    const float* __restrict__ W1, const float* __restrict__ b1,
    const float* __restrict__ W2, const float* __restrict__ b2,
    const float* __restrict__ g, const float* __restrict__ bb,
    float* __restrict__ out)
{
    __shared__ float hs[32][132];
    __shared__ float ffc[32][132];
    __shared__ float mu[32], rstd[32];
    const int tid = threadIdx.x;
    const int r0 = blockIdx.x * 32;
    load_tile32(h, r0, hs, tid);
    __syncthreads();

    const int tx = tid & 31, ty = tid >> 5;
    float acc2[4][4] = {};

    for (int p = 0; p < 4; ++p) {
        // GEMM1 chunk: ff[:, p*128 .. p*128+127] = h @ W1-chunk
        float acc[4][4] = {};
        #pragma unroll 4
        for (int k = 0; k < DM; ++k) {
            float4 bv = *(const float4*)(W1 + k * FF + p * 128 + tx * 4);
            float a0 = hs[ty * 4 + 0][k];
            float a1 = hs[ty * 4 + 1][k];
            float a2 = hs[ty * 4 + 2][k];
            float a3 = hs[ty * 4 + 3][k];
            FMA16(acc, a0, a1, a2, a3, bv);
        }
        float4 bias = *(const float4*)(b1 + p * 128 + tx * 4);
        #pragma unroll
        for (int rr = 0; rr < 4; ++rr) {
            float v0 = acc[rr][0] + bias.x;
            float v1 = acc[rr][1] + bias.y;
            float v2 = acc[rr][2] + bias.z;
            float v3 = acc[rr][3] + bias.w;
            // exact gelu
            v0 = 0.5f * v0 * (1.f + erff(v0 * 0.70710678118654752f));
            v1 = 0.5f * v1 * (1.f + erff(v1 * 0.70710678118654752f));
            v2 = 0.5f * v2 * (1.f + erff(v2 * 0.70710678118654752f));
            v3 = 0.5f * v3 * (1.f + erff(v3 * 0.70710678118654752f));
            *(float4*)&ffc[ty * 4 + rr][tx * 4] = make_float4(v0, v1, v2, v3);
        }
        __syncthreads();
        // GEMM2 partial: acc2 += ffc @ W2[p*128 .. p*128+127, :]
        #pragma unroll 4
        for (int k = 0; k < DM; ++k) {
            float4 bv = *(const float4*)(W2 + (size_t)(p * 128 + k) * DM + tx * 4);
            float a0 = ffc[ty * 4 + 0][k];
            float a1 = ffc[ty * 4 + 1][k];
            float a2 = ffc[ty * 4 + 2][k];
            float a3 = ffc[ty * 4 + 3][k];
            FMA16(acc2, a0, a1, a2, a3, bv);
        }
        __syncthreads();
    }

    // residual + store into hs
    float4 bias2 = *(const float4*)(b2 + tx * 4);
    #pragma unroll
    for (int rr = 0; rr < 4; ++rr) {
        int r = ty * 4 + rr;
        float4 v;
        v.x = acc2[rr][0] + bias2.x + hs[r][tx * 4 + 0];
        v.y = acc2[rr][1] + bias2.y + hs[r][tx * 4 + 1];
        v.z = acc2[rr][2] + bias2.z + hs[r][tx * 4 + 2];
        v.w = acc2[rr][3] + bias2.w + hs[r][tx * 4 + 3];
        *(float4*)&hs[r][tx * 4] = v;
    }
    __syncthreads();

    if (tid < 32) {
        float s = 0.f, q = 0.f;
        #pragma unroll 4
        for (int k = 0; k < DM; ++k) { float v = hs[tid][k]; s += v; q += v * v; }
        float m = s * (1.f / DM);
        float var = q * (1.f / DM) - m * m;
        mu[tid] = m;
        rstd[tid] = rsqrtf(var + 1e-5f);
    }
    __syncthreads();

    int r = tid >> 3, c0 = (tid & 7) * 16;
    int gr = r0 + r;
    if (gr < NN) {
        float m = mu[r], rs = rstd[r];
        #pragma unroll
        for (int i = 0; i < 16; ++i) {
            int c = c0 + i;
            out[(size_t)gr * DM + c] = (hs[r][c] - m) * rs * g[c] + bb[c];
        }
    }
}

// ---------------------------------------------------------------------------
extern "C" void kernel_launch(void* const* d_in, const int* in_sizes, int n_in,
                              void* d_out, int out_size, void* d_ws, size_t ws_size,
                              hipStream_t stream) {
    const float* x   = (const float*)d_in[0];
    const int* row   = (const int*)d_in[1];
    const int* col   = (const int*)d_in[2];
    const int* db    = (const int*)d_in[3];
    const float* Wq  = (const float*)d_in[4];
    const float* bq  = (const float*)d_in[5];
    const float* Wk  = (const float*)d_in[6];
    const float* bk  = (const float*)d_in[7];
    const float* Wv  = (const float*)d_in[8];
    const float* bv  = (const float*)d_in[9];
    const float* Wo  = (const float*)d_in[10];
    const float* bo  = (const float*)d_in[11];
    const float* emb = (const float*)d_in[12];
    const float* g1  = (const float*)d_in[13];
    const float* b1n = (const float*)d_in[14];
    const float* g2  = (const float*)d_in[15];
    const float* b2n = (const float*)d_in[16];
    const float* W1  = (const float*)d_in[17];
    const float* b1  = (const float*)d_in[18];
    const float* W2  = (const float*)d_in[19];
    const float* b2  = (const float*)d_in[20];

    float* ws = (float*)d_ws;
    const size_t NF = (size_t)NN * DM;        // 6.4M floats
    float* Q      = ws;
    float* Kbuf   = ws + NF;
    float* V      = ws + 2 * NF;
    float* scores = ws + 3 * NF;              // E*8 = 6.4M floats
    int*   rowptr = (int*)(ws + 4 * NF);
    float* agg    = Q;                         // alias: Q dead after k_scores
    float* hbuf   = Kbuf;                      // alias: K dead after k_scores

    const int rowblocks = (NN + 31) / 32;     // 1563

    k_rowptr<<<(NN + 1 + 255) / 256, 256, 0, stream>>>(row, rowptr);
    k_qkv<<<rowblocks, 256, 0, stream>>>(x, Wq, bq, Wk, bk, Wv, bv, Q, Kbuf, V);
    k_scores<<<(int)(((long)NE * NH + 255) / 256), 256, 0, stream>>>(Q, Kbuf, row, col, db, emb, scores);
    k_attn<<<NN, 128, 0, stream>>>(scores, V, col, rowptr, agg);
    k_proj_ln1<<<rowblocks, 256, 0, stream>>>(agg, x, Wo, bo, g1, b1n, hbuf);
    k_ffn_ln2<<<rowblocks, 256, 0, stream>>>(hbuf, W1, b1, W2, b2, g2, b2n, (float*)d_out);
}

// Round 2
// 341.449 us; speedup vs baseline: 1.6559x; 1.6559x over previous
//
#include <hip/hip_runtime.h>
#include <math.h>

#define NN 50000
#define NE 800000
#define DM 128
#define NH 8
#define FF 512
#define NBLK 391   // ceil(50000/128)

typedef __attribute__((ext_vector_type(8))) short bf16x8;
typedef __attribute__((ext_vector_type(4))) float f32x4;

__device__ __forceinline__ short f2bf(float f) {
    union { float f; unsigned u; } v; v.f = f;
    unsigned r = v.u + 0x7fff + ((v.u >> 16) & 1);
    return (short)(r >> 16);
}
__device__ __forceinline__ float bf2f(short s) {
    union { unsigned u; float f; } v; v.u = ((unsigned)(unsigned short)s) << 16;
    return v.f;
}

// ---------------------------------------------------------------------------
// async 16B global->LDS
__device__ __forceinline__ void gload16(const void* g, void* l) {
    __builtin_amdgcn_global_load_lds(
        (const __attribute__((address_space(1))) void*)g,
        (__attribute__((address_space(3))) void*)l, 16, 0, 0);
}

// Stage a 128x128 bf16 tile (rows row0..row0+127 of src, cols col0..col0+127,
// row stride ld) into LDS with XOR swizzle: logical slot s of local row lr is
// stored at physical slot s^(lr&7). gload_lds writes linearly, so the global
// SOURCE is pre-swizzled (rule #21) and reads apply the same XOR.
__device__ __forceinline__ void stage_tile(const short* __restrict__ src, int row0,
                                           int maxrow, int ld, int col0,
                                           short* sm) {
    const int tid = threadIdx.x;
    const int w = tid >> 6, l = tid & 63;
    const int p = l & 15;                 // physical slot this lane fills
    #pragma unroll
    for (int j = 0; j < 8; ++j) {
        int lr = w * 32 + j * 4 + (l >> 4);           // local row
        int gr = row0 + lr; gr = gr > maxrow ? maxrow : gr;
        int s = p ^ (lr & 7);                          // logical slot
        const short* g = src + (size_t)gr * ld + col0 + s * 8;
        gload16(g, sm + (w * 32 + j * 4) * 128);       // + lane*16B by HW
    }
}

// read one A/B fragment: outer = local row (A) / local n (B), slot = k/8
__device__ __forceinline__ bf16x8 frag_ld(const short* sm, int outer, int slot) {
    return *(const bf16x8*)(sm + outer * 128 + ((slot ^ (outer & 7)) << 3));
}

// 128x128x128 MFMA: 4 waves in 2x2, each wave 64x64 via 4x4 frags, K=4 steps
__device__ __forceinline__ void mfma_tile(const short* sA, const short* sB,
                                          int wm, int wn, int lane,
                                          f32x4 acc[4][4]) {
    const int l15 = lane & 15, l4 = lane >> 4;
    #pragma unroll
    for (int ks = 0; ks < 4; ++ks) {
        bf16x8 a[4], b[4];
        int slot = ks * 4 + l4;
        #pragma unroll
        for (int f = 0; f < 4; ++f) a[f] = frag_ld(sA, wm * 64 + f * 16 + l15, slot);
        #pragma unroll
        for (int f = 0; f < 4; ++f) b[f] = frag_ld(sB, wn * 64 + f * 16 + l15, slot);
        #pragma unroll
        for (int fm = 0; fm < 4; ++fm)
            #pragma unroll
            for (int fn = 0; fn < 4; ++fn)
                acc[fm][fn] = __builtin_amdgcn_mfma_f32_16x16x32_bf16(
                    a[fm], b[fn], acc[fm][fn], 0, 0, 0);
    }
}

// ---------------------------------------------------------------------------
__global__ void k_rowptr(const int* __restrict__ row, int* __restrict__ rowptr) {
    int n = blockIdx.x * blockDim.x + threadIdx.x;
    if (n > NN) return;
    int lo = 0, hi = NE;
    while (lo < hi) {
        int mid = (lo + hi) >> 1;
        if (row[mid] < n) lo = mid + 1; else hi = mid;
    }
    rowptr[n] = lo;
}

__global__ void k_prep_x(const float* __restrict__ x, short* __restrict__ xb) {
    int i = blockIdx.x * 256 + threadIdx.x;
    if (i >= NN * DM / 4) return;
    float4 v = ((const float4*)x)[i];
    ((short4*)xb)[i] = make_short4(f2bf(v.x), f2bf(v.y), f2bf(v.z), f2bf(v.w));
}

// Wt[n][k] = bf16(W[k][n]); grid (N/32, K/32), 256 threads
__global__ void k_wt(const float* __restrict__ W, short* __restrict__ Wt,
                     int K, int N) {
    __shared__ float t[32][33];
    int n0 = blockIdx.x * 32, k0 = blockIdx.y * 32;
    int r = threadIdx.x >> 3, c4 = (threadIdx.x & 7) * 4;
    float4 v = *(const float4*)(W + (size_t)(k0 + r) * N + n0 + c4);
    t[r][c4 + 0] = v.x; t[r][c4 + 1] = v.y; t[r][c4 + 2] = v.z; t[r][c4 + 3] = v.w;
    __syncthreads();
    short4 o = make_short4(f2bf(t[c4 + 0][r]), f2bf(t[c4 + 1][r]),
                           f2bf(t[c4 + 2][r]), f2bf(t[c4 + 3][r]));
    *(short4*)(Wt + (size_t)(n0 + r) * K + k0 + c4) = o;
}

// ---------------------------------------------------------------------------
// QKV: A = xb tile, loop over 3 transposed weights, bf16 outputs
__global__ __launch_bounds__(256) void k_gemm_qkv(
    const short* __restrict__ xb, const short* __restrict__ Wt,
    const float* __restrict__ bq, const float* __restrict__ bk,
    const float* __restrict__ bv,
    short* __restrict__ Qb, short* __restrict__ Kb, short* __restrict__ Vb)
{
    __shared__ short sm[2 * 16384];
    const int tid = threadIdx.x, lane = tid & 63, wid = tid >> 6;
    const int wm = wid >> 1, wn = wid & 1;
    const int r0 = blockIdx.x * 128;

    stage_tile(xb, r0, NN - 1, 128, 0, sm);
    #pragma unroll
    for (int m = 0; m < 3; ++m) {
        if (m) __syncthreads();
        stage_tile(Wt + m * 16384, 0, 127, 128, 0, sm + 16384);
        __syncthreads();
        f32x4 acc[4][4];
        #pragma unroll
        for (int i = 0; i < 4; ++i)
            #pragma unroll
            for (int j = 0; j < 4; ++j)
                acc[i][j] = (f32x4){0.f, 0.f, 0.f, 0.f};
        mfma_tile(sm, sm + 16384, wm, wn, lane, acc);

        const float* bias = m == 0 ? bq : (m == 1 ? bk : bv);
        short* out = m == 0 ? Qb : (m == 1 ? Kb : Vb);
        #pragma unroll
        for (int fn = 0; fn < 4; ++fn) {
            int col = wn * 64 + fn * 16 + (lane & 15);
            float bc = bias[col];
            #pragma unroll
            for (int fm = 0; fm < 4; ++fm) {
                int rowb = r0 + wm * 64 + fm * 16 + (lane >> 4) * 4;
                #pragma unroll
                for (int rr = 0; rr < 4; ++rr) {
                    int gr = rowb + rr;
                    if (gr < NN)
                        out[(size_t)gr * DM + col] = f2bf(acc[fm][fn][rr] + bc);
                }
            }
        }
    }
}

// ---------------------------------------------------------------------------
__global__ __launch_bounds__(256) void k_scores(
    const short* __restrict__ Qb, const short* __restrict__ Kb,
    const int* __restrict__ row, const int* __restrict__ col,
    const int* __restrict__ db, const float* __restrict__ emb,
    float* __restrict__ scores)
{
    int gid = blockIdx.x * 256 + threadIdx.x;
    if (gid >= NE * NH) return;
    int e = gid >> 3, h = gid & 7;
    int r = row[e], c = col[e];
    const bf16x8* q = (const bf16x8*)(Qb + (size_t)r * DM + h * 16);
    const bf16x8* k = (const bf16x8*)(Kb + (size_t)c * DM + h * 16);
    bf16x8 q0 = q[0], q1 = q[1], k0 = k[0], k1 = k[1];
    float s = 0.f;
    #pragma unroll
    for (int j = 0; j < 8; ++j)
        s += bf2f(q0[j]) * bf2f(k0[j]) + bf2f(q1[j]) * bf2f(k1[j]);
    s *= 0.25f;
    s += emb[db[r] * NH + h] + emb[db[c] * NH + h];
    scores[gid] = s;
}

// ---------------------------------------------------------------------------
__global__ __launch_bounds__(128) void k_attn(
    const float* __restrict__ scores, const short* __restrict__ Vb,
    const int* __restrict__ col, const int* __restrict__ rowptr,
    short* __restrict__ aggb)
{
    const int n = blockIdx.x;
    const int tid = threadIdx.x;
    const int e0 = rowptr[n], e1 = rowptr[n + 1];

    __shared__ float red[128];
    __shared__ float mh[NH], sh[NH];

    const int h = tid & 7;
    const int s = tid >> 3;

    float m = -INFINITY;
    for (int e = e0 + s; e < e1; e += 16) m = fmaxf(m, scores[(size_t)e * NH + h]);
    red[tid] = m;
    __syncthreads();
    if (tid < NH) {
        float mm = -INFINITY;
        #pragma unroll
        for (int i = 0; i < 16; ++i) mm = fmaxf(mm, red[tid + 8 * i]);
        mh[tid] = mm;
    }
    __syncthreads();

    float mm = mh[h];
    float sum = 0.f;
    for (int e = e0 + s; e < e1; e += 16) sum += expf(scores[(size_t)e * NH + h] - mm);
    red[tid] = sum;
    __syncthreads();
    if (tid < NH) {
        float ss = 0.f;
        #pragma unroll
        for (int i = 0; i < 16; ++i) ss += red[tid + 8 * i];
        sh[tid] = fmaxf(ss, 1e-12f);
    }
    __syncthreads();

    const int th = tid >> 4;
    const float mb = mh[th];
    const float sb = sh[th];
    float acc = 0.f;
    for (int e = e0; e < e1; ++e) {
        int c = col[e];
        float alpha = expf(scores[(size_t)e * NH + th] - mb) / sb;
        acc += alpha * bf2f(Vb[(size_t)c * DM + tid]);
    }
    aggb[(size_t)n * DM + tid] = f2bf(acc);
}

// ---------------------------------------------------------------------------
// agg@Wo + bo + x -> LN1 -> h (f32) and hb (bf16)
__global__ __launch_bounds__(256) void k_gemm_ln1(
    const short* __restrict__ aggb, const short* __restrict__ Wot,
    const float* __restrict__ bo, const float* __restrict__ x,
    const float* __restrict__ g, const float* __restrict__ b,
    float* __restrict__ h, short* __restrict__ hb)
{
    __shared__ union { short ab[2 * 16384]; float hs[128 * 129]; } u;
    __shared__ float mu[128], rsd[128];
    const int tid = threadIdx.x, lane = tid & 63, wid = tid >> 6;
    const int wm = wid >> 1, wn = wid & 1;
    const int r0 = blockIdx.x * 128;

    stage_tile(aggb, r0, NN - 1, 128, 0, u.ab);
    stage_tile(Wot, 0, 127, 128, 0, u.ab + 16384);
    __syncthreads();

    f32x4 acc[4][4];
    #pragma unroll
    for (int i = 0; i < 4; ++i)
        #pragma unroll
        for (int j = 0; j < 4; ++j) acc[i][j] = (f32x4){0.f, 0.f, 0.f, 0.f};
    mfma_tile(u.ab, u.ab + 16384, wm, wn, lane, acc);
    __syncthreads();   // done reading ab; hs overlays it

    #pragma unroll
    for (int fn = 0; fn < 4; ++fn) {
        int col = wn * 64 + fn * 16 + (lane & 15);
        float bc = bo[col];
        #pragma unroll
        for (int fm = 0; fm < 4; ++fm) {
            int rowb = wm * 64 + fm * 16 + (lane >> 4) * 4;
            #pragma unroll
            for (int rr = 0; rr < 4; ++rr) {
                int r_ = rowb + rr, gr = r0 + r_;
                float xr = (gr < NN) ? x[(size_t)gr * DM + col] : 0.f;
                u.hs[r_ * 129 + col] = acc[fm][fn][rr] + bc + xr;
            }
        }
    }
    __syncthreads();

    {
        int rrow = tid >> 1, half = tid & 1;
        float s = 0.f, q = 0.f;
        #pragma unroll 8
        for (int c = 0; c < 64; ++c) {
            float v = u.hs[rrow * 129 + half * 64 + c];
            s += v; q += v * v;
        }
        s += __shfl_xor(s, 1);
        q += __shfl_xor(q, 1);
        float m = s * (1.f / DM);
        float var = q * (1.f / DM) - m * m;
        if (half == 0) { mu[rrow] = m; rsd[rrow] = rsqrtf(var + 1e-5f); }
    }
    __syncthreads();

    for (int i = 0; i < 64; ++i) {
        int idx = i * 256 + tid;
        int rrow = idx >> 7, c = idx & 127;
        int gr = r0 + rrow;
        if (gr < NN) {
            float v = (u.hs[rrow * 129 + c] - mu[rrow]) * rsd[rrow] * g[c] + b[c];
            h[(size_t)gr * DM + c] = v;
            hb[(size_t)gr * DM + c] = f2bf(v);
        }
    }
}

// ---------------------------------------------------------------------------
// FFN up: hb@W1 + b1 -> gelu -> ffb (bf16).  grid (NBLK, 4)
__global__ __launch_bounds__(256) void k_gemm1(
    const short* __restrict__ hb, const short* __restrict__ Wt1,
    const float* __restrict__ b1, short* __restrict__ ffb)
{
    __shared__ short sm[2 * 16384];
    const int tid = threadIdx.x, lane = tid & 63, wid = tid >> 6;
    const int wm = wid >> 1, wn = wid & 1;
    const int r0 = blockIdx.x * 128;
    const int n0 = blockIdx.y * 128;

    stage_tile(hb, r0, NN - 1, 128, 0, sm);
    stage_tile(Wt1 + (size_t)n0 * 128, 0, 127, 128, 0, sm + 16384);
    __syncthreads();

    f32x4 acc[4][4];
    #pragma unroll
    for (int i = 0; i < 4; ++i)
        #pragma unroll
        for (int j = 0; j < 4; ++j) acc[i][j] = (f32x4){0.f, 0.f, 0.f, 0.f};
    mfma_tile(sm, sm + 16384, wm, wn, lane, acc);

    #pragma unroll
    for (int fn = 0; fn < 4; ++fn) {
        int colg = n0 + wn * 64 + fn * 16 + (lane & 15);
        float bc = b1[colg];
        #pragma unroll
        for (int fm = 0; fm < 4; ++fm) {
            int rowb = r0 + wm * 64 + fm * 16 + (lane >> 4) * 4;
            #pragma unroll
            for (int rr = 0; rr < 4; ++rr) {
                int gr = rowb + rr;
                if (gr < NN) {
                    float v = acc[fm][fn][rr] + bc;
                    v = 0.5f * v * (1.f + erff(v * 0.70710678118654752f));
                    ffb[(size_t)gr * FF + colg] = f2bf(v);
                }
            }
        }
    }
}

// ---------------------------------------------------------------------------
// FFN down: ffb@W2 + b2 + h -> LN2 -> out (f32)
__global__ __launch_bounds__(256) void k_gemm2(
    const short* __restrict__ ffb, const short* __restrict__ Wt2,
    const float* __restrict__ b2, const float* __restrict__ h,
    const float* __restrict__ g, const float* __restrict__ b,
    float* __restrict__ out)
{
    __shared__ union { short ab[2 * 16384]; float hs[128 * 129]; } u;
    __shared__ float mu[128], rsd[128];
    const int tid = threadIdx.x, lane = tid & 63, wid = tid >> 6;
    const int wm = wid >> 1, wn = wid & 1;
    const int r0 = blockIdx.x * 128;

    f32x4 acc[4][4];
    #pragma unroll
    for (int i = 0; i < 4; ++i)
        #pragma unroll
        for (int j = 0; j < 4; ++j) acc[i][j] = (f32x4){0.f, 0.f, 0.f, 0.f};

    for (int kc = 0; kc < 4; ++kc) {
        if (kc) __syncthreads();
        stage_tile(ffb, r0, NN - 1, FF, kc * 128, u.ab);
        stage_tile(Wt2, 0, 127, FF, kc * 128, u.ab + 16384);
        __syncthreads();
        mfma_tile(u.ab, u.ab + 16384, wm, wn, lane, acc);
    }
    __syncthreads();

    #pragma unroll
    for (int fn = 0; fn < 4; ++fn) {
        int col = wn * 64 + fn * 16 + (lane & 15);
        float bc = b2[col];
        #pragma unroll
        for (int fm = 0; fm < 4; ++fm) {
            int rowb = wm * 64 + fm * 16 + (lane >> 4) * 4;
            #pragma unroll
            for (int rr = 0; rr < 4; ++rr) {
                int r_ = rowb + rr, gr = r0 + r_;
                float hr = (gr < NN) ? h[(size_t)gr * DM + col] : 0.f;
                u.hs[r_ * 129 + col] = acc[fm][fn][rr] + bc + hr;
            }
        }
    }
    __syncthreads();

    {
        int rrow = tid >> 1, half = tid & 1;
        float s = 0.f, q = 0.f;
        #pragma unroll 8
        for (int c = 0; c < 64; ++c) {
            float v = u.hs[rrow * 129 + half * 64 + c];
            s += v; q += v * v;
        }
        s += __shfl_xor(s, 1);
        q += __shfl_xor(q, 1);
        float m = s * (1.f / DM);
        float var = q * (1.f / DM) - m * m;
        if (half == 0) { mu[rrow] = m; rsd[rrow] = rsqrtf(var + 1e-5f); }
    }
    __syncthreads();

    for (int i = 0; i < 64; ++i) {
        int idx = i * 256 + tid;
        int rrow = idx >> 7, c = idx & 127;
        int gr = r0 + rrow;
        if (gr < NN)
            out[(size_t)gr * DM + c] =
                (u.hs[rrow * 129 + c] - mu[rrow]) * rsd[rrow] * g[c] + b[c];
    }
}

// ---------------------------------------------------------------------------
extern "C" void kernel_launch(void* const* d_in, const int* in_sizes, int n_in,
                              void* d_out, int out_size, void* d_ws, size_t ws_size,
                              hipStream_t stream) {
    const float* x   = (const float*)d_in[0];
    const int* row   = (const int*)d_in[1];
    const int* col   = (const int*)d_in[2];
    const int* db    = (const int*)d_in[3];
    const float* Wq  = (const float*)d_in[4];
    const float* bq  = (const float*)d_in[5];
    const float* Wk  = (const float*)d_in[6];
    const float* bk  = (const float*)d_in[7];
    const float* Wv  = (const float*)d_in[8];
    const float* bv  = (const float*)d_in[9];
    const float* Wo  = (const float*)d_in[10];
    const float* bo  = (const float*)d_in[11];
    const float* emb = (const float*)d_in[12];
    const float* g1  = (const float*)d_in[13];
    const float* b1n = (const float*)d_in[14];
    const float* g2  = (const float*)d_in[15];
    const float* b2n = (const float*)d_in[16];
    const float* W1  = (const float*)d_in[17];
    const float* b1  = (const float*)d_in[18];
    const float* W2  = (const float*)d_in[19];
    const float* b2  = (const float*)d_in[20];

    char* W = (char*)d_ws;
    // zone0 (51.2 MB): scores | aggb | xb  -> later overlaid by ffb
    float* scores = (float*)(W + 0);             // 25,600,000 B
    short* aggb   = (short*)(W + 25600000);      // 12,800,000 B
    short* xb     = (short*)(W + 38400000);      // 12,800,000 B
    short* ffb    = (short*)(W + 0);             // 51,200,000 B (overlay)
    // zone1 (25.6 MB): Qb | Kb -> later overlaid by h (f32)
    short* Qb     = (short*)(W + 51200000);
    short* Kb     = (short*)(W + 64000000);
    float* h      = (float*)(W + 51200000);      // overlay
    // zone2 (12.8 MB): Vb -> later hb
    short* Vb     = (short*)(W + 76800000);
    short* hb     = (short*)(W + 76800000);      // overlay
    // zone3: bf16 transposed weights + rowptr
    short* wts    = (short*)(W + 89600000);      // 393,216 B
    int* rowptr   = (int*)(W + 89993216);        // 200,004 B

    k_prep_x<<<(NN * DM / 4 + 255) / 256, 256, 0, stream>>>(x, xb);
    k_wt<<<dim3(4, 4), 256, 0, stream>>>(Wq, wts + 0, 128, 128);
    k_wt<<<dim3(4, 4), 256, 0, stream>>>(Wk, wts + 16384, 128, 128);
    k_wt<<<dim3(4, 4), 256, 0, stream>>>(Wv, wts + 32768, 128, 128);
    k_wt<<<dim3(4, 4), 256, 0, stream>>>(Wo, wts + 49152, 128, 128);
    k_wt<<<dim3(16, 4), 256, 0, stream>>>(W1, wts + 65536, 128, 512);
    k_wt<<<dim3(4, 16), 256, 0, stream>>>(W2, wts + 131072, 512, 128);
    k_rowptr<<<(NN + 1 + 255) / 256, 256, 0, stream>>>(row, rowptr);

    k_gemm_qkv<<<NBLK, 256, 0, stream>>>(xb, wts, bq, bk, bv, Qb, Kb, Vb);
    k_scores<<<NE * NH / 256, 256, 0, stream>>>(Qb, Kb, row, col, db, emb, scores);
    k_attn<<<NN, 128, 0, stream>>>(scores, Vb, col, rowptr, aggb);
    k_gemm_ln1<<<NBLK, 256, 0, stream>>>(aggb, wts + 49152, bo, x, g1, b1n, h, hb);
    k_gemm1<<<dim3(NBLK, 4), 256, 0, stream>>>(hb, wts + 65536, b1, ffb);
    k_gemm2<<<NBLK, 256, 0, stream>>>(ffb, wts + 131072, b2, h, g2, b2n, (float*)d_out);
}

// Round 3
// 268.265 us; speedup vs baseline: 2.1077x; 1.2728x over previous
//
#include <hip/hip_runtime.h>
#include <math.h>

#define NN 50000
#define NE 800000
#define DM 128
#define NH 8
#define FF 512
#define NBLK 391   // ceil(50000/128)

typedef __attribute__((ext_vector_type(8))) short bf16x8;
typedef __attribute__((ext_vector_type(4))) float f32x4;

__device__ __forceinline__ short f2bf(float f) {
    union { float f; unsigned u; } v; v.f = f;
    unsigned r = v.u + 0x7fff + ((v.u >> 16) & 1);
    return (short)(r >> 16);
}
__device__ __forceinline__ float bf2f(short s) {
    union { unsigned u; float f; } v; v.u = ((unsigned)(unsigned short)s) << 16;
    return v.f;
}

// ---------------------------------------------------------------------------
// async 16B global->LDS
__device__ __forceinline__ void gload16(const void* g, void* l) {
    __builtin_amdgcn_global_load_lds(
        (const __attribute__((address_space(1))) void*)g,
        (__attribute__((address_space(3))) void*)l, 16, 0, 0);
}

// Stage a 128x128 bf16 tile into LDS with XOR swizzle (inverse-swizzled
// global source + linear LDS dest; reads apply the same XOR — rule #21).
__device__ __forceinline__ void stage_tile(const short* __restrict__ src, int row0,
                                           int maxrow, int ld, int col0,
                                           short* sm) {
    const int tid = threadIdx.x;
    const int w = tid >> 6, l = tid & 63;
    const int p = l & 15;                 // physical slot this lane fills
    #pragma unroll
    for (int j = 0; j < 8; ++j) {
        int lr = w * 32 + j * 4 + (l >> 4);           // local row
        int gr = row0 + lr; gr = gr > maxrow ? maxrow : gr;
        int s = p ^ (lr & 7);                          // logical slot
        const short* g = src + (size_t)gr * ld + col0 + s * 8;
        gload16(g, sm + (w * 32 + j * 4) * 128);       // + lane*16B by HW
    }
}

__device__ __forceinline__ bf16x8 frag_ld(const short* sm, int outer, int slot) {
    return *(const bf16x8*)(sm + outer * 128 + ((slot ^ (outer & 7)) << 3));
}

// 128x128x128 MFMA: 4 waves in 2x2, each wave 64x64 via 4x4 frags
__device__ __forceinline__ void mfma_tile(const short* sA, const short* sB,
                                          int wm, int wn, int lane,
                                          f32x4 acc[4][4]) {
    const int l15 = lane & 15, l4 = lane >> 4;
    #pragma unroll
    for (int ks = 0; ks < 4; ++ks) {
        bf16x8 a[4], b[4];
        int slot = ks * 4 + l4;
        #pragma unroll
        for (int f = 0; f < 4; ++f) a[f] = frag_ld(sA, wm * 64 + f * 16 + l15, slot);
        #pragma unroll
        for (int f = 0; f < 4; ++f) b[f] = frag_ld(sB, wn * 64 + f * 16 + l15, slot);
        #pragma unroll
        for (int fm = 0; fm < 4; ++fm)
            #pragma unroll
            for (int fn = 0; fn < 4; ++fn)
                acc[fm][fn] = __builtin_amdgcn_mfma_f32_16x16x32_bf16(
                    a[fm], b[fn], acc[fm][fn], 0, 0, 0);
    }
}

// ---------------------------------------------------------------------------
__global__ void k_rowptr(const int* __restrict__ row, int* __restrict__ rowptr) {
    int n = blockIdx.x * blockDim.x + threadIdx.x;
    if (n > NN) return;
    int lo = 0, hi = NE;
    while (lo < hi) {
        int mid = (lo + hi) >> 1;
        if (row[mid] < n) lo = mid + 1; else hi = mid;
    }
    rowptr[n] = lo;
}

__global__ void k_prep_x(const float* __restrict__ x, short* __restrict__ xb) {
    int i = blockIdx.x * 256 + threadIdx.x;
    if (i >= NN * DM / 4) return;
    float4 v = ((const float4*)x)[i];
    ((short4*)xb)[i] = make_short4(f2bf(v.x), f2bf(v.y), f2bf(v.z), f2bf(v.w));
}

// Wt[n][k] = bf16(W[k][n]); grid (N/32, K/32), 256 threads
__global__ void k_wt(const float* __restrict__ W, short* __restrict__ Wt,
                     int K, int N) {
    __shared__ float t[32][33];
    int n0 = blockIdx.x * 32, k0 = blockIdx.y * 32;
    int r = threadIdx.x >> 3, c4 = (threadIdx.x & 7) * 4;
    float4 v = *(const float4*)(W + (size_t)(k0 + r) * N + n0 + c4);
    t[r][c4 + 0] = v.x; t[r][c4 + 1] = v.y; t[r][c4 + 2] = v.z; t[r][c4 + 3] = v.w;
    __syncthreads();
    short4 o = make_short4(f2bf(t[c4 + 0][r]), f2bf(t[c4 + 1][r]),
                           f2bf(t[c4 + 2][r]), f2bf(t[c4 + 3][r]));
    *(short4*)(Wt + (size_t)(n0 + r) * K + k0 + c4) = o;
}

// ---------------------------------------------------------------------------
__global__ __launch_bounds__(256) void k_gemm_qkv(
    const short* __restrict__ xb, const short* __restrict__ Wt,
    const float* __restrict__ bq, const float* __restrict__ bk,
    const float* __restrict__ bv,
    short* __restrict__ Qb, short* __restrict__ Kb, short* __restrict__ Vb)
{
    __shared__ short sm[2 * 16384];
    const int tid = threadIdx.x, lane = tid & 63, wid = tid >> 6;
    const int wm = wid >> 1, wn = wid & 1;
    const int r0 = blockIdx.x * 128;

    stage_tile(xb, r0, NN - 1, 128, 0, sm);
    #pragma unroll
    for (int m = 0; m < 3; ++m) {
        if (m) __syncthreads();
        stage_tile(Wt + m * 16384, 0, 127, 128, 0, sm + 16384);
        __syncthreads();
        f32x4 acc[4][4];
        #pragma unroll
        for (int i = 0; i < 4; ++i)
            #pragma unroll
            for (int j = 0; j < 4; ++j)
                acc[i][j] = (f32x4){0.f, 0.f, 0.f, 0.f};
        mfma_tile(sm, sm + 16384, wm, wn, lane, acc);

        const float* bias = m == 0 ? bq : (m == 1 ? bk : bv);
        short* out = m == 0 ? Qb : (m == 1 ? Kb : Vb);
        #pragma unroll
        for (int fn = 0; fn < 4; ++fn) {
            int col = wn * 64 + fn * 16 + (lane & 15);
            float bc = bias[col];
            #pragma unroll
            for (int fm = 0; fm < 4; ++fm) {
                int rowb = r0 + wm * 64 + fm * 16 + (lane >> 4) * 4;
                #pragma unroll
                for (int rr = 0; rr < 4; ++rr) {
                    int gr = rowb + rr;
                    if (gr < NN)
                        out[(size_t)gr * DM + col] = f2bf(acc[fm][fn][rr] + bc);
                }
            }
        }
    }
}

// ---------------------------------------------------------------------------
// Fused edge-scores + segment softmax (online) + V aggregation.
// One 128-thread block per destination node.
__global__ __launch_bounds__(128) void k_attn_fused(
    const short* __restrict__ Qb, const short* __restrict__ Kb,
    const short* __restrict__ Vb, const int* __restrict__ col,
    const int* __restrict__ rowptr, const int* __restrict__ db,
    const float* __restrict__ emb, short* __restrict__ aggb)
{
    const int n = blockIdx.x;
    const int tid = threadIdx.x;
    const int e0 = rowptr[n], e1 = rowptr[n + 1];

    __shared__ float sc[16][8];   // chunk scores [slot][head]
    __shared__ float pp[16][8];   // chunk exp()
    __shared__ int colc[16];
    __shared__ float mh[8], fh[8], lh[8];

    const int s = tid >> 3, h = tid & 7;   // score-phase mapping
    const int h2 = tid >> 4;               // agg-phase: dim = tid, head = h2

    if (tid < 8) { mh[tid] = -INFINITY; lh[tid] = 0.f; }

    // preload Q[n][h*16 .. h*16+15] to registers (f32)
    float qf[16];
    {
        const bf16x8* qp = (const bf16x8*)(Qb + (size_t)n * DM + h * 16);
        bf16x8 q0 = qp[0], q1 = qp[1];
        #pragma unroll
        for (int j = 0; j < 8; ++j) { qf[j] = bf2f(q0[j]); qf[8 + j] = bf2f(q1[j]); }
    }
    const float embr = emb[db[n] * NH + h];
    float acc = 0.f;
    __syncthreads();

    for (int c0 = e0; c0 < e1; c0 += 16) {
        // --- score phase: 16 edge slots x 8 heads
        int e = c0 + s;
        float scv = -INFINITY;
        if (e < e1) {
            int c = col[e];
            if (h == 0) colc[s] = c;
            const bf16x8* kp = (const bf16x8*)(Kb + (size_t)c * DM + h * 16);
            bf16x8 k0 = kp[0], k1 = kp[1];
            float d = 0.f;
            #pragma unroll
            for (int j = 0; j < 8; ++j)
                d += qf[j] * bf2f(k0[j]) + qf[8 + j] * bf2f(k1[j]);
            scv = d * 0.25f + embr + emb[db[c] * NH + h];
        }
        sc[s][h] = scv;
        __syncthreads();

        // --- running max + rescale factor per head
        if (tid < 8) {
            float mc = -INFINITY;
            #pragma unroll
            for (int i = 0; i < 16; ++i) mc = fmaxf(mc, sc[i][tid]);
            float mn = fmaxf(mh[tid], mc);
            fh[tid] = __expf(mh[tid] - mn);   // exp(-inf)=0 on first chunk
            mh[tid] = mn;
        }
        __syncthreads();

        // --- p = exp(score - m_new), once per (edge, head)
        float p = __expf(scv - mh[h]);        // scv=-inf -> 0 for invalid slots
        pp[s][h] = p;
        __syncthreads();

        // --- running sum (8 threads) runs concurrently with aggregation
        if (tid < 8) {
            float ssum = 0.f;
            #pragma unroll
            for (int i = 0; i < 16; ++i) ssum += pp[i][tid];
            lh[tid] = lh[tid] * fh[tid] + ssum;
        }

        // --- aggregation: thread tid owns output dim tid (head h2)
        acc *= fh[h2];
        int nv = e1 - c0; nv = nv > 16 ? 16 : nv;
        for (int j = 0; j < nv; ++j) {
            int c = colc[j];
            acc += pp[j][h2] * bf2f(Vb[(size_t)c * DM + tid]);
        }
        __syncthreads();   // protect sc/pp/colc/lh for next chunk
    }

    float l = fmaxf(lh[h2], 1e-12f);
    aggb[(size_t)n * DM + tid] = f2bf(acc / l);
}

// ---------------------------------------------------------------------------
// agg@Wo + bo + x -> LN1 -> h (f32) and hb (bf16)
__global__ __launch_bounds__(256) void k_gemm_ln1(
    const short* __restrict__ aggb, const short* __restrict__ Wot,
    const float* __restrict__ bo, const float* __restrict__ x,
    const float* __restrict__ g, const float* __restrict__ b,
    float* __restrict__ h, short* __restrict__ hb)
{
    __shared__ union { short ab[2 * 16384]; float hs[128 * 129]; } u;
    __shared__ float mu[128], rsd[128];
    const int tid = threadIdx.x, lane = tid & 63, wid = tid >> 6;
    const int wm = wid >> 1, wn = wid & 1;
    const int r0 = blockIdx.x * 128;

    stage_tile(aggb, r0, NN - 1, 128, 0, u.ab);
    stage_tile(Wot, 0, 127, 128, 0, u.ab + 16384);
    __syncthreads();

    f32x4 acc[4][4];
    #pragma unroll
    for (int i = 0; i < 4; ++i)
        #pragma unroll
        for (int j = 0; j < 4; ++j) acc[i][j] = (f32x4){0.f, 0.f, 0.f, 0.f};
    mfma_tile(u.ab, u.ab + 16384, wm, wn, lane, acc);
    __syncthreads();   // done reading ab; hs overlays it

    #pragma unroll
    for (int fn = 0; fn < 4; ++fn) {
        int col = wn * 64 + fn * 16 + (lane & 15);
        float bc = bo[col];
        #pragma unroll
        for (int fm = 0; fm < 4; ++fm) {
            int rowb = wm * 64 + fm * 16 + (lane >> 4) * 4;
            #pragma unroll
            for (int rr = 0; rr < 4; ++rr) {
                int r_ = rowb + rr, gr = r0 + r_;
                float xr = (gr < NN) ? x[(size_t)gr * DM + col] : 0.f;
                u.hs[r_ * 129 + col] = acc[fm][fn][rr] + bc + xr;
            }
        }
    }
    __syncthreads();

    {
        int rrow = tid >> 1, half = tid & 1;
        float s = 0.f, q = 0.f;
        #pragma unroll 8
        for (int c = 0; c < 64; ++c) {
            float v = u.hs[rrow * 129 + half * 64 + c];
            s += v; q += v * v;
        }
        s += __shfl_xor(s, 1);
        q += __shfl_xor(q, 1);
        float m = s * (1.f / DM);
        float var = q * (1.f / DM) - m * m;
        if (half == 0) { mu[rrow] = m; rsd[rrow] = rsqrtf(var + 1e-5f); }
    }
    __syncthreads();

    for (int i = 0; i < 64; ++i) {
        int idx = i * 256 + tid;
        int rrow = idx >> 7, c = idx & 127;
        int gr = r0 + rrow;
        if (gr < NN) {
            float v = (u.hs[rrow * 129 + c] - mu[rrow]) * rsd[rrow] * g[c] + b[c];
            h[(size_t)gr * DM + c] = v;
            hb[(size_t)gr * DM + c] = f2bf(v);
        }
    }
}

// ---------------------------------------------------------------------------
// FFN up: hb@W1 + b1 -> gelu -> ffb (bf16).  grid (NBLK, 4)
__global__ __launch_bounds__(256) void k_gemm1(
    const short* __restrict__ hb, const short* __restrict__ Wt1,
    const float* __restrict__ b1, short* __restrict__ ffb)
{
    __shared__ short sm[2 * 16384];
    const int tid = threadIdx.x, lane = tid & 63, wid = tid >> 6;
    const int wm = wid >> 1, wn = wid & 1;
    const int r0 = blockIdx.x * 128;
    const int n0 = blockIdx.y * 128;

    stage_tile(hb, r0, NN - 1, 128, 0, sm);
    stage_tile(Wt1 + (size_t)n0 * 128, 0, 127, 128, 0, sm + 16384);
    __syncthreads();

    f32x4 acc[4][4];
    #pragma unroll
    for (int i = 0; i < 4; ++i)
        #pragma unroll
        for (int j = 0; j < 4; ++j) acc[i][j] = (f32x4){0.f, 0.f, 0.f, 0.f};
    mfma_tile(sm, sm + 16384, wm, wn, lane, acc);

    #pragma unroll
    for (int fn = 0; fn < 4; ++fn) {
        int colg = n0 + wn * 64 + fn * 16 + (lane & 15);
        float bc = b1[colg];
        #pragma unroll
        for (int fm = 0; fm < 4; ++fm) {
            int rowb = r0 + wm * 64 + fm * 16 + (lane >> 4) * 4;
            #pragma unroll
            for (int rr = 0; rr < 4; ++rr) {
                int gr = rowb + rr;
                if (gr < NN) {
                    float v = acc[fm][fn][rr] + bc;
                    v = 0.5f * v * (1.f + erff(v * 0.70710678118654752f));
                    ffb[(size_t)gr * FF + colg] = f2bf(v);
                }
            }
        }
    }
}

// ---------------------------------------------------------------------------
// FFN down: ffb@W2 + b2 + h -> LN2 -> out (f32)
__global__ __launch_bounds__(256) void k_gemm2(
    const short* __restrict__ ffb, const short* __restrict__ Wt2,
    const float* __restrict__ b2, const float* __restrict__ h,
    const float* __restrict__ g, const float* __restrict__ b,
    float* __restrict__ out)
{
    __shared__ union { short ab[2 * 16384]; float hs[128 * 129]; } u;
    __shared__ float mu[128], rsd[128];
    const int tid = threadIdx.x, lane = tid & 63, wid = tid >> 6;
    const int wm = wid >> 1, wn = wid & 1;
    const int r0 = blockIdx.x * 128;

    f32x4 acc[4][4];
    #pragma unroll
    for (int i = 0; i < 4; ++i)
        #pragma unroll
        for (int j = 0; j < 4; ++j) acc[i][j] = (f32x4){0.f, 0.f, 0.f, 0.f};

    for (int kc = 0; kc < 4; ++kc) {
        if (kc) __syncthreads();
        stage_tile(ffb, r0, NN - 1, FF, kc * 128, u.ab);
        stage_tile(Wt2, 0, 127, FF, kc * 128, u.ab + 16384);
        __syncthreads();
        mfma_tile(u.ab, u.ab + 16384, wm, wn, lane, acc);
    }
    __syncthreads();

    #pragma unroll
    for (int fn = 0; fn < 4; ++fn) {
        int col = wn * 64 + fn * 16 + (lane & 15);
        float bc = b2[col];
        #pragma unroll
        for (int fm = 0; fm < 4; ++fm) {
            int rowb = wm * 64 + fm * 16 + (lane >> 4) * 4;
            #pragma unroll
            for (int rr = 0; rr < 4; ++rr) {
                int r_ = rowb + rr, gr = r0 + r_;
                float hr = (gr < NN) ? h[(size_t)gr * DM + col] : 0.f;
                u.hs[r_ * 129 + col] = acc[fm][fn][rr] + bc + hr;
            }
        }
    }
    __syncthreads();

    {
        int rrow = tid >> 1, half = tid & 1;
        float s = 0.f, q = 0.f;
        #pragma unroll 8
        for (int c = 0; c < 64; ++c) {
            float v = u.hs[rrow * 129 + half * 64 + c];
            s += v; q += v * v;
        }
        s += __shfl_xor(s, 1);
        q += __shfl_xor(q, 1);
        float m = s * (1.f / DM);
        float var = q * (1.f / DM) - m * m;
        if (half == 0) { mu[rrow] = m; rsd[rrow] = rsqrtf(var + 1e-5f); }
    }
    __syncthreads();

    for (int i = 0; i < 64; ++i) {
        int idx = i * 256 + tid;
        int rrow = idx >> 7, c = idx & 127;
        int gr = r0 + rrow;
        if (gr < NN)
            out[(size_t)gr * DM + c] =
                (u.hs[rrow * 129 + c] - mu[rrow]) * rsd[rrow] * g[c] + b[c];
    }
}

// ---------------------------------------------------------------------------
extern "C" void kernel_launch(void* const* d_in, const int* in_sizes, int n_in,
                              void* d_out, int out_size, void* d_ws, size_t ws_size,
                              hipStream_t stream) {
    const float* x   = (const float*)d_in[0];
    const int* row   = (const int*)d_in[1];
    const int* col   = (const int*)d_in[2];
    const int* db    = (const int*)d_in[3];
    const float* Wq  = (const float*)d_in[4];
    const float* bq  = (const float*)d_in[5];
    const float* Wk  = (const float*)d_in[6];
    const float* bk  = (const float*)d_in[7];
    const float* Wv  = (const float*)d_in[8];
    const float* bv  = (const float*)d_in[9];
    const float* Wo  = (const float*)d_in[10];
    const float* bo  = (const float*)d_in[11];
    const float* emb = (const float*)d_in[12];
    const float* g1  = (const float*)d_in[13];
    const float* b1n = (const float*)d_in[14];
    const float* g2  = (const float*)d_in[15];
    const float* b2n = (const float*)d_in[16];
    const float* W1  = (const float*)d_in[17];
    const float* b1  = (const float*)d_in[18];
    const float* W2  = (const float*)d_in[19];
    const float* b2  = (const float*)d_in[20];

    char* W = (char*)d_ws;
    // zone0 (51.2 MB): aggb | xb  -> later overlaid by ffb
    short* aggb   = (short*)(W + 25600000);      // 12,800,000 B
    short* xb     = (short*)(W + 38400000);      // 12,800,000 B
    short* ffb    = (short*)(W + 0);             // 51,200,000 B (overlay)
    // zone1 (25.6 MB): Qb | Kb -> later overlaid by h (f32)
    short* Qb     = (short*)(W + 51200000);
    short* Kb     = (short*)(W + 64000000);
    float* h      = (float*)(W + 51200000);      // overlay
    // zone2 (12.8 MB): Vb -> later hb
    short* Vb     = (short*)(W + 76800000);
    short* hb     = (short*)(W + 76800000);      // overlay
    // zone3: bf16 transposed weights + rowptr
    short* wts    = (short*)(W + 89600000);      // 393,216 B
    int* rowptr   = (int*)(W + 89993216);        // 200,004 B

    k_prep_x<<<(NN * DM / 4 + 255) / 256, 256, 0, stream>>>(x, xb);
    k_wt<<<dim3(4, 4), 256, 0, stream>>>(Wq, wts + 0, 128, 128);
    k_wt<<<dim3(4, 4), 256, 0, stream>>>(Wk, wts + 16384, 128, 128);
    k_wt<<<dim3(4, 4), 256, 0, stream>>>(Wv, wts + 32768, 128, 128);
    k_wt<<<dim3(4, 4), 256, 0, stream>>>(Wo, wts + 49152, 128, 128);
    k_wt<<<dim3(16, 4), 256, 0, stream>>>(W1, wts + 65536, 128, 512);
    k_wt<<<dim3(4, 16), 256, 0, stream>>>(W2, wts + 131072, 512, 128);
    k_rowptr<<<(NN + 1 + 255) / 256, 256, 0, stream>>>(row, rowptr);

    k_gemm_qkv<<<NBLK, 256, 0, stream>>>(xb, wts, bq, bk, bv, Qb, Kb, Vb);
    k_attn_fused<<<NN, 128, 0, stream>>>(Qb, Kb, Vb, col, rowptr, db, emb, aggb);
    k_gemm_ln1<<<NBLK, 256, 0, stream>>>(aggb, wts + 49152, bo, x, g1, b1n, h, hb);
    k_gemm1<<<dim3(NBLK, 4), 256, 0, stream>>>(hb, wts + 65536, b1, ffb);
    k_gemm2<<<NBLK, 256, 0, stream>>>(ffb, wts + 131072, b2, h, g2, b2n, (float*)d_out);
}

// Round 4
// 245.398 us; speedup vs baseline: 2.3041x; 1.0932x over previous
//
#include <hip/hip_runtime.h>
#include <math.h>

#define NN 50000
#define NE 800000
#define DM 128
#define NH 8
#define FF 512
#define NBLK 391    // ceil(50000/128)
#define NBLK64 782  // ceil(50000/64)

typedef __attribute__((ext_vector_type(8))) short bf16x8;
typedef __attribute__((ext_vector_type(4))) float f32x4;

__device__ __forceinline__ short f2bf(float f) {
    union { float f; unsigned u; } v; v.f = f;
    unsigned r = v.u + 0x7fff + ((v.u >> 16) & 1);
    return (short)(r >> 16);
}
__device__ __forceinline__ float bf2f(short s) {
    union { unsigned u; float f; } v; v.u = ((unsigned)(unsigned short)s) << 16;
    return v.f;
}

// ---------------------------------------------------------------------------
__device__ __forceinline__ void gload16(const void* g, void* l) {
    __builtin_amdgcn_global_load_lds(
        (const __attribute__((address_space(1))) void*)g,
        (__attribute__((address_space(3))) void*)l, 16, 0, 0);
}

// Stage 128x128 bf16 tile with XOR swizzle (inverse-swizzled global source +
// linear LDS dest; reads apply same XOR — rule #21).
__device__ __forceinline__ void stage_tile(const short* __restrict__ src, int row0,
                                           int maxrow, int ld, int col0,
                                           short* sm) {
    const int tid = threadIdx.x;
    const int w = tid >> 6, l = tid & 63;
    const int p = l & 15;
    #pragma unroll
    for (int j = 0; j < 8; ++j) {
        int lr = w * 32 + j * 4 + (l >> 4);
        int gr = row0 + lr; gr = gr > maxrow ? maxrow : gr;
        int s = p ^ (lr & 7);
        const short* g = src + (size_t)gr * ld + col0 + s * 8;
        gload16(g, sm + (w * 32 + j * 4) * 128);
    }
}

// Stage 64x128 bf16 tile, same swizzle.
__device__ __forceinline__ void stage_tile64(const short* __restrict__ src, int row0,
                                             int maxrow, int ld, int col0,
                                             short* sm) {
    const int tid = threadIdx.x;
    const int w = tid >> 6, l = tid & 63;
    const int p = l & 15;
    #pragma unroll
    for (int j = 0; j < 4; ++j) {
        int lr = w * 16 + j * 4 + (l >> 4);
        int gr = row0 + lr; gr = gr > maxrow ? maxrow : gr;
        int s = p ^ (lr & 7);
        const short* g = src + (size_t)gr * ld + col0 + s * 8;
        gload16(g, sm + (w * 16 + j * 4) * 128);
    }
}

__device__ __forceinline__ bf16x8 frag_ld(const short* sm, int outer, int slot) {
    return *(const bf16x8*)(sm + outer * 128 + ((slot ^ (outer & 7)) << 3));
}

// 128x128x128: 4 waves 2x2, each 64x64
__device__ __forceinline__ void mfma_tile(const short* sA, const short* sB,
                                          int wm, int wn, int lane,
                                          f32x4 acc[4][4]) {
    const int l15 = lane & 15, l4 = lane >> 4;
    #pragma unroll
    for (int ks = 0; ks < 4; ++ks) {
        bf16x8 a[4], b[4];
        int slot = ks * 4 + l4;
        #pragma unroll
        for (int f = 0; f < 4; ++f) a[f] = frag_ld(sA, wm * 64 + f * 16 + l15, slot);
        #pragma unroll
        for (int f = 0; f < 4; ++f) b[f] = frag_ld(sB, wn * 64 + f * 16 + l15, slot);
        #pragma unroll
        for (int fm = 0; fm < 4; ++fm)
            #pragma unroll
            for (int fn = 0; fn < 4; ++fn)
                acc[fm][fn] = __builtin_amdgcn_mfma_f32_16x16x32_bf16(
                    a[fm], b[fn], acc[fm][fn], 0, 0, 0);
    }
}

// 64x128x128: 4 waves 2x2, each 32m x 64n
__device__ __forceinline__ void mfma_tile64(const short* sA, const short* sB,
                                            int wm, int wn, int lane,
                                            f32x4 acc[2][4]) {
    const int l15 = lane & 15, l4 = lane >> 4;
    #pragma unroll
    for (int ks = 0; ks < 4; ++ks) {
        bf16x8 a[2], b[4];
        int slot = ks * 4 + l4;
        #pragma unroll
        for (int f = 0; f < 2; ++f) a[f] = frag_ld(sA, wm * 32 + f * 16 + l15, slot);
        #pragma unroll
        for (int f = 0; f < 4; ++f) b[f] = frag_ld(sB, wn * 64 + f * 16 + l15, slot);
        #pragma unroll
        for (int fm = 0; fm < 2; ++fm)
            #pragma unroll
            for (int fn = 0; fn < 4; ++fn)
                acc[fm][fn] = __builtin_amdgcn_mfma_f32_16x16x32_bf16(
                    a[fm], b[fn], acc[fm][fn], 0, 0, 0);
    }
}

// ---------------------------------------------------------------------------
__global__ void k_rowptr(const int* __restrict__ row, int* __restrict__ rowptr) {
    int n = blockIdx.x * blockDim.x + threadIdx.x;
    if (n > NN) return;
    int lo = 0, hi = NE;
    while (lo < hi) {
        int mid = (lo + hi) >> 1;
        if (row[mid] < n) lo = mid + 1; else hi = mid;
    }
    rowptr[n] = lo;
}

__global__ void k_prep_x(const float* __restrict__ x, short* __restrict__ xb) {
    int i = blockIdx.x * 256 + threadIdx.x;
    if (i >= NN * DM / 4) return;
    float4 v = ((const float4*)x)[i];
    ((short4*)xb)[i] = make_short4(f2bf(v.x), f2bf(v.y), f2bf(v.z), f2bf(v.w));
}

__global__ void k_wt(const float* __restrict__ W, short* __restrict__ Wt,
                     int K, int N) {
    __shared__ float t[32][33];
    int n0 = blockIdx.x * 32, k0 = blockIdx.y * 32;
    int r = threadIdx.x >> 3, c4 = (threadIdx.x & 7) * 4;
    float4 v = *(const float4*)(W + (size_t)(k0 + r) * N + n0 + c4);
    t[r][c4 + 0] = v.x; t[r][c4 + 1] = v.y; t[r][c4 + 2] = v.z; t[r][c4 + 3] = v.w;
    __syncthreads();
    short4 o = make_short4(f2bf(t[c4 + 0][r]), f2bf(t[c4 + 1][r]),
                           f2bf(t[c4 + 2][r]), f2bf(t[c4 + 3][r]));
    *(short4*)(Wt + (size_t)(n0 + r) * K + k0 + c4) = o;
}

// ---------------------------------------------------------------------------
__global__ __launch_bounds__(256) void k_gemm_qkv(
    const short* __restrict__ xb, const short* __restrict__ Wt,
    const float* __restrict__ bq, const float* __restrict__ bk,
    const float* __restrict__ bv,
    short* __restrict__ Qb, short* __restrict__ Kb, short* __restrict__ Vb)
{
    __shared__ short sm[2 * 16384];
    const int tid = threadIdx.x, lane = tid & 63, wid = tid >> 6;
    const int wm = wid >> 1, wn = wid & 1;
    const int r0 = blockIdx.x * 128;

    stage_tile(xb, r0, NN - 1, 128, 0, sm);
    #pragma unroll
    for (int m = 0; m < 3; ++m) {
        if (m) __syncthreads();
        stage_tile(Wt + m * 16384, 0, 127, 128, 0, sm + 16384);
        __syncthreads();
        f32x4 acc[4][4];
        #pragma unroll
        for (int i = 0; i < 4; ++i)
            #pragma unroll
            for (int j = 0; j < 4; ++j)
                acc[i][j] = (f32x4){0.f, 0.f, 0.f, 0.f};
        mfma_tile(sm, sm + 16384, wm, wn, lane, acc);

        const float* bias = m == 0 ? bq : (m == 1 ? bk : bv);
        short* out = m == 0 ? Qb : (m == 1 ? Kb : Vb);
        #pragma unroll
        for (int fn = 0; fn < 4; ++fn) {
            int col = wn * 64 + fn * 16 + (lane & 15);
            float bc = bias[col];
            #pragma unroll
            for (int fm = 0; fm < 4; ++fm) {
                int rowb = r0 + wm * 64 + fm * 16 + (lane >> 4) * 4;
                #pragma unroll
                for (int rr = 0; rr < 4; ++rr) {
                    int gr = rowb + rr;
                    if (gr < NN)
                        out[(size_t)gr * DM + col] = f2bf(acc[fm][fn][rr] + bc);
                }
            }
        }
    }
}

// ---------------------------------------------------------------------------
// Wave-per-node fused attention: scores + online segment softmax + V agg.
// One wave64 per node, 4 nodes per block, zero LDS / zero barriers.
__global__ __launch_bounds__(256) void k_attn_wave(
    const short* __restrict__ Qb, const short* __restrict__ Kb,
    const short* __restrict__ Vb, const int* __restrict__ col,
    const int* __restrict__ rowptr, const int* __restrict__ db,
    const float* __restrict__ emb, short* __restrict__ aggb)
{
    const int lane = threadIdx.x & 63;
    const int n = blockIdx.x * 4 + (threadIdx.x >> 6);
    const int e0 = rowptr[n], e1 = rowptr[n + 1];
    const int s = lane >> 3, h = lane & 7;   // score phase: slot, head
    const int h2 = lane >> 3;                // agg phase: head for dims 2*lane..+1

    float qf[16];
    {
        const bf16x8* qp = (const bf16x8*)(Qb + (size_t)n * DM + h * 16);
        bf16x8 q0 = qp[0], q1 = qp[1];
        #pragma unroll
        for (int j = 0; j < 8; ++j) { qf[j] = bf2f(q0[j]); qf[8 + j] = bf2f(q1[j]); }
    }
    const float embr = emb[db[n] * NH + h];

    float m = -INFINITY, l = 0.f, acc0 = 0.f, acc1 = 0.f;

    for (int c0 = e0; c0 < e1; c0 += 8) {
        int e = c0 + s;
        bool valid = e < e1;
        int c = col[valid ? e : e1 - 1];
        const bf16x8* kp = (const bf16x8*)(Kb + (size_t)c * DM + h * 16);
        bf16x8 k0 = kp[0], k1 = kp[1];
        float d = 0.f;
        #pragma unroll
        for (int j = 0; j < 8; ++j)
            d += qf[j] * bf2f(k0[j]) + qf[8 + j] * bf2f(k1[j]);
        float scv = valid ? (d * 0.25f + embr + emb[db[c] * NH + h]) : -INFINITY;

        // per-head max over the 8 slots (lanes differing in bits 3..5)
        float mc = scv;
        mc = fmaxf(mc, __shfl_xor(mc, 8));
        mc = fmaxf(mc, __shfl_xor(mc, 16));
        mc = fmaxf(mc, __shfl_xor(mc, 32));
        float mn = fmaxf(m, mc);
        float f = __expf(m - mn);            // exp(-inf)=0 first time
        m = mn;
        float p = __expf(scv - mn);          // invalid -> 0
        float ps = p;
        ps += __shfl_xor(ps, 8);
        ps += __shfl_xor(ps, 16);
        ps += __shfl_xor(ps, 32);
        l = l * f + ps;

        float fa = __shfl(f, h2);
        acc0 *= fa; acc1 *= fa;
        int nv = e1 - c0; nv = nv > 8 ? 8 : nv;
        for (int j = 0; j < nv; ++j) {
            int cj = __shfl(c, j * 8);
            float pj = __shfl(p, j * 8 + h2);
            const ushort2 v = *(const ushort2*)(Vb + (size_t)cj * DM + lane * 2);
            acc0 += pj * bf2f((short)v.x);
            acc1 += pj * bf2f((short)v.y);
        }
    }
    float la = __shfl(l, h2);
    la = fmaxf(la, 1e-12f);
    ushort2 o;
    o.x = (unsigned short)f2bf(acc0 / la);
    o.y = (unsigned short)f2bf(acc1 / la);
    *(ushort2*)(aggb + (size_t)n * DM + lane * 2) = o;
}

// ---------------------------------------------------------------------------
// agg@Wo + bo + x -> LN1 -> h (f32) and hb (bf16)
__global__ __launch_bounds__(256) void k_gemm_ln1(
    const short* __restrict__ aggb, const short* __restrict__ Wot,
    const float* __restrict__ bo, const float* __restrict__ x,
    const float* __restrict__ g, const float* __restrict__ b,
    float* __restrict__ h, short* __restrict__ hb)
{
    __shared__ union { short ab[2 * 16384]; float hs[128 * 129]; } u;
    __shared__ float mu[128], rsd[128];
    const int tid = threadIdx.x, lane = tid & 63, wid = tid >> 6;
    const int wm = wid >> 1, wn = wid & 1;
    const int r0 = blockIdx.x * 128;

    stage_tile(aggb, r0, NN - 1, 128, 0, u.ab);
    stage_tile(Wot, 0, 127, 128, 0, u.ab + 16384);
    __syncthreads();

    f32x4 acc[4][4];
    #pragma unroll
    for (int i = 0; i < 4; ++i)
        #pragma unroll
        for (int j = 0; j < 4; ++j) acc[i][j] = (f32x4){0.f, 0.f, 0.f, 0.f};
    mfma_tile(u.ab, u.ab + 16384, wm, wn, lane, acc);
    __syncthreads();

    #pragma unroll
    for (int fn = 0; fn < 4; ++fn) {
        int col = wn * 64 + fn * 16 + (lane & 15);
        float bc = bo[col];
        #pragma unroll
        for (int fm = 0; fm < 4; ++fm) {
            int rowb = wm * 64 + fm * 16 + (lane >> 4) * 4;
            #pragma unroll
            for (int rr = 0; rr < 4; ++rr) {
                int r_ = rowb + rr, gr = r0 + r_;
                float xr = (gr < NN) ? x[(size_t)gr * DM + col] : 0.f;
                u.hs[r_ * 129 + col] = acc[fm][fn][rr] + bc + xr;
            }
        }
    }
    __syncthreads();

    {
        int rrow = tid >> 1, half = tid & 1;
        float s = 0.f, q = 0.f;
        #pragma unroll 8
        for (int c = 0; c < 64; ++c) {
            float v = u.hs[rrow * 129 + half * 64 + c];
            s += v; q += v * v;
        }
        s += __shfl_xor(s, 1);
        q += __shfl_xor(q, 1);
        float m = s * (1.f / DM);
        float var = q * (1.f / DM) - m * m;
        if (half == 0) { mu[rrow] = m; rsd[rrow] = rsqrtf(var + 1e-5f); }
    }
    __syncthreads();

    for (int i = 0; i < 64; ++i) {
        int idx = i * 256 + tid;
        int rrow = idx >> 7, c = idx & 127;
        int gr = r0 + rrow;
        if (gr < NN) {
            float v = (u.hs[rrow * 129 + c] - mu[rrow]) * rsd[rrow] * g[c] + b[c];
            h[(size_t)gr * DM + c] = v;
            hb[(size_t)gr * DM + c] = f2bf(v);
        }
    }
}

// ---------------------------------------------------------------------------
// Fused FFN: gelu(hb@W1+b1)@W2 + b2 + h -> LN2 -> out.  BM=64, 64KB dyn LDS.
// Layout: A[64x128] hb tile | B[128x128] weight chunk | C[64x128] ff tile.
__global__ __launch_bounds__(256) void k_ffn_fused(
    const short* __restrict__ hb, const short* __restrict__ Wt1,
    const float* __restrict__ b1, const short* __restrict__ Wt2,
    const float* __restrict__ b2, const float* __restrict__ h,
    const float* __restrict__ g, const float* __restrict__ bb,
    float* __restrict__ out)
{
    extern __shared__ char smraw[];
    short* A = (short*)smraw;          // 16 KB
    short* B = A + 8192;               // 32 KB
    short* C = B + 16384;              // 16 KB
    float* hs = (float*)smraw;         // overlay after gemms: 64*129*4 = 33 KB
    __shared__ float mu[64], rsd[64];

    const int tid = threadIdx.x, lane = tid & 63, wid = tid >> 6;
    const int wm = wid >> 1, wn = wid & 1;
    const int r0 = blockIdx.x * 64;

    f32x4 acc2[2][4];
    #pragma unroll
    for (int i = 0; i < 2; ++i)
        #pragma unroll
        for (int j = 0; j < 4; ++j) acc2[i][j] = (f32x4){0.f, 0.f, 0.f, 0.f};

    stage_tile64(hb, r0, NN - 1, 128, 0, A);

    for (int kc = 0; kc < 4; ++kc) {
        if (kc) __syncthreads();                    // prev mfma2 done with B,C
        stage_tile(Wt1, kc * 128, FF - 1, 128, 0, B);
        __syncthreads();                            // A (first iter) + W1c ready

        f32x4 accf[2][4];
        #pragma unroll
        for (int i = 0; i < 2; ++i)
            #pragma unroll
            for (int j = 0; j < 4; ++j) accf[i][j] = (f32x4){0.f, 0.f, 0.f, 0.f};
        mfma_tile64(A, B, wm, wn, lane, accf);

        // gelu -> C (frag_ld-compatible swizzled bf16 writes)
        #pragma unroll
        for (int fn = 0; fn < 4; ++fn) {
            int nloc = wn * 64 + fn * 16 + (lane & 15);
            float bc = b1[kc * 128 + nloc];
            int slot = nloc >> 3;
            #pragma unroll
            for (int fm = 0; fm < 2; ++fm) {
                int rowb = wm * 32 + fm * 16 + (lane >> 4) * 4;
                #pragma unroll
                for (int rr = 0; rr < 4; ++rr) {
                    int row = rowb + rr;
                    float v = accf[fm][fn][rr] + bc;
                    v = 0.5f * v * (1.f + erff(v * 0.70710678118654752f));
                    C[row * 128 + (((slot ^ (row & 7)) << 3) | (nloc & 7))] = f2bf(v);
                }
            }
        }
        __syncthreads();                            // C visible, B free
        stage_tile(Wt2, 0, 127, FF, kc * 128, B);
        __syncthreads();                            // W2c ready
        mfma_tile64(C, B, wm, wn, lane, acc2);
    }
    __syncthreads();                                // all LDS reads done; overlay hs

    #pragma unroll
    for (int fn = 0; fn < 4; ++fn) {
        int col = wn * 64 + fn * 16 + (lane & 15);
        float bc = b2[col];
        #pragma unroll
        for (int fm = 0; fm < 2; ++fm) {
            int rowb = wm * 32 + fm * 16 + (lane >> 4) * 4;
            #pragma unroll
            for (int rr = 0; rr < 4; ++rr) {
                int r_ = rowb + rr, gr = r0 + r_;
                float hr = (gr < NN) ? h[(size_t)gr * DM + col] : 0.f;
                hs[r_ * 129 + col] = acc2[fm][fn][rr] + bc + hr;
            }
        }
    }
    __syncthreads();

    {
        int rrow = tid >> 2, q = tid & 3;
        float s = 0.f, qq = 0.f;
        #pragma unroll 8
        for (int c = 0; c < 32; ++c) {
            float v = hs[rrow * 129 + q * 32 + c];
            s += v; qq += v * v;
        }
        s += __shfl_xor(s, 1);  qq += __shfl_xor(qq, 1);
        s += __shfl_xor(s, 2);  qq += __shfl_xor(qq, 2);
        float m = s * (1.f / DM);
        float var = qq * (1.f / DM) - m * m;
        if (q == 0) { mu[rrow] = m; rsd[rrow] = rsqrtf(var + 1e-5f); }
    }
    __syncthreads();

    for (int i = 0; i < 32; ++i) {
        int idx = i * 256 + tid;
        int rrow = idx >> 7, c = idx & 127;
        int gr = r0 + rrow;
        if (gr < NN)
            out[(size_t)gr * DM + c] =
                (hs[rrow * 129 + c] - mu[rrow]) * rsd[rrow] * g[c] + bb[c];
    }
}

// ---------------------------------------------------------------------------
extern "C" void kernel_launch(void* const* d_in, const int* in_sizes, int n_in,
                              void* d_out, int out_size, void* d_ws, size_t ws_size,
                              hipStream_t stream) {
    const float* x   = (const float*)d_in[0];
    const int* row   = (const int*)d_in[1];
    const int* col   = (const int*)d_in[2];
    const int* db    = (const int*)d_in[3];
    const float* Wq  = (const float*)d_in[4];
    const float* bq  = (const float*)d_in[5];
    const float* Wk  = (const float*)d_in[6];
    const float* bk  = (const float*)d_in[7];
    const float* Wv  = (const float*)d_in[8];
    const float* bv  = (const float*)d_in[9];
    const float* Wo  = (const float*)d_in[10];
    const float* bo  = (const float*)d_in[11];
    const float* emb = (const float*)d_in[12];
    const float* g1  = (const float*)d_in[13];
    const float* b1n = (const float*)d_in[14];
    const float* g2  = (const float*)d_in[15];
    const float* b2n = (const float*)d_in[16];
    const float* W1  = (const float*)d_in[17];
    const float* b1  = (const float*)d_in[18];
    const float* W2  = (const float*)d_in[19];
    const float* b2  = (const float*)d_in[20];

    char* W = (char*)d_ws;
    short* aggb   = (short*)(W + 25600000);
    short* xb     = (short*)(W + 38400000);
    short* Qb     = (short*)(W + 51200000);
    short* Kb     = (short*)(W + 64000000);
    float* h      = (float*)(W + 51200000);      // overlay (Qb/Kb dead)
    short* Vb     = (short*)(W + 76800000);
    short* hb     = (short*)(W + 76800000);      // overlay (Vb dead)
    short* wts    = (short*)(W + 89600000);
    int* rowptr   = (int*)(W + 89993216);

    k_prep_x<<<(NN * DM / 4 + 255) / 256, 256, 0, stream>>>(x, xb);
    k_wt<<<dim3(4, 4), 256, 0, stream>>>(Wq, wts + 0, 128, 128);
    k_wt<<<dim3(4, 4), 256, 0, stream>>>(Wk, wts + 16384, 128, 128);
    k_wt<<<dim3(4, 4), 256, 0, stream>>>(Wv, wts + 32768, 128, 128);
    k_wt<<<dim3(4, 4), 256, 0, stream>>>(Wo, wts + 49152, 128, 128);
    k_wt<<<dim3(16, 4), 256, 0, stream>>>(W1, wts + 65536, 128, 512);
    k_wt<<<dim3(4, 16), 256, 0, stream>>>(W2, wts + 131072, 512, 128);
    k_rowptr<<<(NN + 1 + 255) / 256, 256, 0, stream>>>(row, rowptr);

    k_gemm_qkv<<<NBLK, 256, 0, stream>>>(xb, wts, bq, bk, bv, Qb, Kb, Vb);
    k_attn_wave<<<NN / 4, 256, 0, stream>>>(Qb, Kb, Vb, col, rowptr, db, emb, aggb);
    k_gemm_ln1<<<NBLK, 256, 0, stream>>>(aggb, wts + 49152, bo, x, g1, b1n, h, hb);
    k_ffn_fused<<<NBLK64, 256, 65536, stream>>>(hb, wts + 65536, b1,
                                                wts + 131072, b2, h, g2, b2n,
                                                (float*)d_out);
}

// Round 5
// 221.560 us; speedup vs baseline: 2.5520x; 1.1076x over previous
//
#include <hip/hip_runtime.h>
#include <math.h>

#define NN 50000
#define NE 800000
#define DM 128
#define NH 8
#define FF 512
#define NBLK 391    // ceil(50000/128)
#define NBLK64 782  // ceil(50000/64)

// merged prep kernel block ranges
#define PB_X    6250          // x->bf16 blocks
#define PB_WT   192           // weight transpose blocks
#define PB_RP   196           // rowptr blocks
#define PB_EMB  1563          // embn blocks
#define PB_TOT  (PB_X + PB_WT + PB_RP + PB_EMB)

typedef __attribute__((ext_vector_type(8))) short bf16x8;
typedef __attribute__((ext_vector_type(4))) float f32x4;

__device__ __forceinline__ short f2bf(float f) {
    union { float f; unsigned u; } v; v.f = f;
    unsigned r = v.u + 0x7fff + ((v.u >> 16) & 1);
    return (short)(r >> 16);
}
__device__ __forceinline__ float bf2f(short s) {
    union { unsigned u; float f; } v; v.u = ((unsigned)(unsigned short)s) << 16;
    return v.f;
}
__device__ __forceinline__ float u2f(unsigned u) {
    union { unsigned u; float f; } v; v.u = u; return v.f;
}

// ---------------------------------------------------------------------------
__device__ __forceinline__ void gload16(const void* g, void* l) {
    __builtin_amdgcn_global_load_lds(
        (const __attribute__((address_space(1))) void*)g,
        (__attribute__((address_space(3))) void*)l, 16, 0, 0);
}

// Stage 128x128 bf16 tile with XOR swizzle (inverse-swizzled global source +
// linear LDS dest; reads apply same XOR — rule #21).
__device__ __forceinline__ void stage_tile(const short* __restrict__ src, int row0,
                                           int maxrow, int ld, int col0,
                                           short* sm) {
    const int tid = threadIdx.x;
    const int w = tid >> 6, l = tid & 63;
    const int p = l & 15;
    #pragma unroll
    for (int j = 0; j < 8; ++j) {
        int lr = w * 32 + j * 4 + (l >> 4);
        int gr = row0 + lr; gr = gr > maxrow ? maxrow : gr;
        int s = p ^ (lr & 7);
        const short* g = src + (size_t)gr * ld + col0 + s * 8;
        gload16(g, sm + (w * 32 + j * 4) * 128);
    }
}

__device__ __forceinline__ void stage_tile64(const short* __restrict__ src, int row0,
                                             int maxrow, int ld, int col0,
                                             short* sm) {
    const int tid = threadIdx.x;
    const int w = tid >> 6, l = tid & 63;
    const int p = l & 15;
    #pragma unroll
    for (int j = 0; j < 4; ++j) {
        int lr = w * 16 + j * 4 + (l >> 4);
        int gr = row0 + lr; gr = gr > maxrow ? maxrow : gr;
        int s = p ^ (lr & 7);
        const short* g = src + (size_t)gr * ld + col0 + s * 8;
        gload16(g, sm + (w * 16 + j * 4) * 128);
    }
}

__device__ __forceinline__ bf16x8 frag_ld(const short* sm, int outer, int slot) {
    return *(const bf16x8*)(sm + outer * 128 + ((slot ^ (outer & 7)) << 3));
}

__device__ __forceinline__ void mfma_tile(const short* sA, const short* sB,
                                          int wm, int wn, int lane,
                                          f32x4 acc[4][4]) {
    const int l15 = lane & 15, l4 = lane >> 4;
    #pragma unroll
    for (int ks = 0; ks < 4; ++ks) {
        bf16x8 a[4], b[4];
        int slot = ks * 4 + l4;
        #pragma unroll
        for (int f = 0; f < 4; ++f) a[f] = frag_ld(sA, wm * 64 + f * 16 + l15, slot);
        #pragma unroll
        for (int f = 0; f < 4; ++f) b[f] = frag_ld(sB, wn * 64 + f * 16 + l15, slot);
        #pragma unroll
        for (int fm = 0; fm < 4; ++fm)
            #pragma unroll
            for (int fn = 0; fn < 4; ++fn)
                acc[fm][fn] = __builtin_amdgcn_mfma_f32_16x16x32_bf16(
                    a[fm], b[fn], acc[fm][fn], 0, 0, 0);
    }
}

__device__ __forceinline__ void mfma_tile64(const short* sA, const short* sB,
                                            int wm, int wn, int lane,
                                            f32x4 acc[2][4]) {
    const int l15 = lane & 15, l4 = lane >> 4;
    #pragma unroll
    for (int ks = 0; ks < 4; ++ks) {
        bf16x8 a[2], b[4];
        int slot = ks * 4 + l4;
        #pragma unroll
        for (int f = 0; f < 2; ++f) a[f] = frag_ld(sA, wm * 32 + f * 16 + l15, slot);
        #pragma unroll
        for (int f = 0; f < 4; ++f) b[f] = frag_ld(sB, wn * 64 + f * 16 + l15, slot);
        #pragma unroll
        for (int fm = 0; fm < 2; ++fm)
            #pragma unroll
            for (int fn = 0; fn < 4; ++fn)
                acc[fm][fn] = __builtin_amdgcn_mfma_f32_16x16x32_bf16(
                    a[fm], b[fn], acc[fm][fn], 0, 0, 0);
    }
}

// ---------------------------------------------------------------------------
// Merged prep: x->bf16 | 6 weight transposes | rowptr | embn materialization.
__global__ __launch_bounds__(256) void k_prep(
    const float* __restrict__ x, short* __restrict__ xb,
    const float* __restrict__ Wq, const float* __restrict__ Wk,
    const float* __restrict__ Wv, const float* __restrict__ Wo,
    const float* __restrict__ W1, const float* __restrict__ W2,
    short* __restrict__ wts,
    const int* __restrict__ row, int* __restrict__ rowptr,
    const int* __restrict__ db, const float* __restrict__ emb,
    float* __restrict__ embn)
{
    int bid = blockIdx.x;
    const int tid = threadIdx.x;

    if (bid < PB_X) {                       // x -> bf16
        int i = bid * 256 + tid;
        if (i < NN * DM / 4) {
            float4 v = ((const float4*)x)[i];
            ((short4*)xb)[i] = make_short4(f2bf(v.x), f2bf(v.y), f2bf(v.z), f2bf(v.w));
        }
        return;
    }
    bid -= PB_X;
    if (bid < PB_WT) {                      // weight transposes
        const float* W; short* Wt; int K, N, bx, by;
        if (bid < 64) {
            int wsel = bid >> 4, rel = bid & 15;
            W = wsel == 0 ? Wq : wsel == 1 ? Wk : wsel == 2 ? Wv : Wo;
            Wt = wts + wsel * 16384; K = 128; N = 128; bx = rel & 3; by = rel >> 2;
        } else if (bid < 128) {
            int rel = bid - 64;
            W = W1; Wt = wts + 65536; K = 128; N = 512; bx = rel & 15; by = rel >> 4;
        } else {
            int rel = bid - 128;
            W = W2; Wt = wts + 131072; K = 512; N = 128; bx = rel & 3; by = rel >> 2;
        }
        __shared__ float t[32][33];
        int n0 = bx * 32, k0 = by * 32;
        int r = tid >> 3, c4 = (tid & 7) * 4;
        float4 v = *(const float4*)(W + (size_t)(k0 + r) * N + n0 + c4);
        t[r][c4 + 0] = v.x; t[r][c4 + 1] = v.y; t[r][c4 + 2] = v.z; t[r][c4 + 3] = v.w;
        __syncthreads();
        short4 o = make_short4(f2bf(t[c4 + 0][r]), f2bf(t[c4 + 1][r]),
                               f2bf(t[c4 + 2][r]), f2bf(t[c4 + 3][r]));
        *(short4*)(Wt + (size_t)(n0 + r) * K + k0 + c4) = o;
        return;
    }
    bid -= PB_WT;
    if (bid < PB_RP) {                      // rowptr via binary search
        int n = bid * 256 + tid;
        if (n > NN) return;
        int lo = 0, hi = NE;
        while (lo < hi) {
            int mid = (lo + hi) >> 1;
            if (row[mid] < n) lo = mid + 1; else hi = mid;
        }
        rowptr[n] = lo;
        return;
    }
    bid -= PB_RP;
    {                                       // embn[n*8+h] = emb[db[n]*8+h]
        int i = bid * 256 + tid;
        if (i < NN * NH) embn[i] = emb[db[i >> 3] * NH + (i & 7)];
    }
}

// ---------------------------------------------------------------------------
__global__ __launch_bounds__(256) void k_gemm_qkv(
    const short* __restrict__ xb, const short* __restrict__ Wt,
    const float* __restrict__ bq, const float* __restrict__ bk,
    const float* __restrict__ bv,
    short* __restrict__ Qb, short* __restrict__ Kb, short* __restrict__ Vb)
{
    __shared__ short sm[2 * 16384];
    const int tid = threadIdx.x, lane = tid & 63, wid = tid >> 6;
    const int wm = wid >> 1, wn = wid & 1;
    const int r0 = blockIdx.x * 128;

    stage_tile(xb, r0, NN - 1, 128, 0, sm);
    #pragma unroll
    for (int m = 0; m < 3; ++m) {
        if (m) __syncthreads();
        stage_tile(Wt + m * 16384, 0, 127, 128, 0, sm + 16384);
        __syncthreads();
        f32x4 acc[4][4];
        #pragma unroll
        for (int i = 0; i < 4; ++i)
            #pragma unroll
            for (int j = 0; j < 4; ++j)
                acc[i][j] = (f32x4){0.f, 0.f, 0.f, 0.f};
        mfma_tile(sm, sm + 16384, wm, wn, lane, acc);

        const float* bias = m == 0 ? bq : (m == 1 ? bk : bv);
        short* out = m == 0 ? Qb : (m == 1 ? Kb : Vb);
        #pragma unroll
        for (int fn = 0; fn < 4; ++fn) {
            int col = wn * 64 + fn * 16 + (lane & 15);
            float bc = bias[col];
            #pragma unroll
            for (int fm = 0; fm < 4; ++fm) {
                int rowb = r0 + wm * 64 + fm * 16 + (lane >> 4) * 4;
                #pragma unroll
                for (int rr = 0; rr < 4; ++rr) {
                    int gr = rowb + rr;
                    if (gr < NN)
                        out[(size_t)gr * DM + col] = f2bf(acc[fm][fn][rr] + bc);
                }
            }
        }
    }
}

// ---------------------------------------------------------------------------
// Wave-per-node fused attention, 16-edge chunks, V preloaded alongside K.
__global__ __launch_bounds__(256) void k_attn_wave(
    const short* __restrict__ Qb, const short* __restrict__ Kb,
    const short* __restrict__ Vb, const int* __restrict__ col,
    const int* __restrict__ rowptr, const float* __restrict__ embn,
    short* __restrict__ aggb)
{
    const int lane = threadIdx.x & 63;
    const int n = blockIdx.x * 4 + (threadIdx.x >> 6);
    const int e0 = rowptr[n], e1 = rowptr[n + 1];
    const int s = lane >> 3, h = lane & 7;   // score phase: slot, head
    const int h2 = lane >> 3;                // agg phase: head owning dims 2lane..+1

    float qf[16];
    {
        const bf16x8* qp = (const bf16x8*)(Qb + (size_t)n * DM + h * 16);
        bf16x8 q0 = qp[0], q1 = qp[1];
        #pragma unroll
        for (int j = 0; j < 8; ++j) { qf[j] = bf2f(q0[j]); qf[8 + j] = bf2f(q1[j]); }
    }
    const float embr = embn[(size_t)n * NH + h];

    float m = -INFINITY, l = 0.f, acc0 = 0.f, acc1 = 0.f;

    for (int c0 = e0; c0 < e1; c0 += 16) {
        int ea = c0 + s, eb = c0 + 8 + s;
        bool va = ea < e1, vb = eb < e1;
        int ca = col[va ? ea : e1 - 1];
        int cb = col[vb ? eb : e1 - 1];

        // K gathers for both slots (issue together)
        const bf16x8* kpa = (const bf16x8*)(Kb + (size_t)ca * DM + h * 16);
        const bf16x8* kpb = (const bf16x8*)(Kb + (size_t)cb * DM + h * 16);
        bf16x8 ka0 = kpa[0], ka1 = kpa[1];
        bf16x8 kb0 = kpb[0], kb1 = kpb[1];
        float ema = embn[(size_t)ca * NH + h];
        float emB = embn[(size_t)cb * NH + h];

        // V preload for up to 16 edges (independent of scores)
        int nv = e1 - c0; nv = nv > 16 ? 16 : nv;
        unsigned vv[16];
        #pragma unroll
        for (int j = 0; j < 8; ++j) {
            int cj = __shfl(ca, j * 8);
            vv[j] = (j < nv) ? *(const unsigned*)(Vb + (size_t)cj * DM + lane * 2) : 0u;
        }
        #pragma unroll
        for (int j = 0; j < 8; ++j) {
            int cj = __shfl(cb, j * 8);
            vv[8 + j] = (8 + j < nv) ? *(const unsigned*)(Vb + (size_t)cj * DM + lane * 2) : 0u;
        }

        float da = 0.f, dbv = 0.f;
        #pragma unroll
        for (int j = 0; j < 8; ++j) {
            da  += qf[j] * bf2f(ka0[j]) + qf[8 + j] * bf2f(ka1[j]);
            dbv += qf[j] * bf2f(kb0[j]) + qf[8 + j] * bf2f(kb1[j]);
        }
        float sa = va ? da * 0.25f + embr + ema : -INFINITY;
        float sb = vb ? dbv * 0.25f + embr + emB : -INFINITY;

        float mc = fmaxf(sa, sb);
        mc = fmaxf(mc, __shfl_xor(mc, 8));
        mc = fmaxf(mc, __shfl_xor(mc, 16));
        mc = fmaxf(mc, __shfl_xor(mc, 32));
        float mn = fmaxf(m, mc);
        float f = __expf(m - mn);            // exp(-inf)=0 first chunk
        m = mn;
        float pa = __expf(sa - mn);
        float pb = __expf(sb - mn);
        float ps = pa + pb;
        ps += __shfl_xor(ps, 8);
        ps += __shfl_xor(ps, 16);
        ps += __shfl_xor(ps, 32);
        l = l * f + ps;

        float fr = __shfl(f, h2);
        acc0 *= fr; acc1 *= fr;
        #pragma unroll
        for (int j = 0; j < 8; ++j) {
            float pj = __shfl(pa, j * 8 + h2);
            acc0 += pj * u2f(vv[j] << 16);
            acc1 += pj * u2f(vv[j] & 0xffff0000u);
        }
        #pragma unroll
        for (int j = 0; j < 8; ++j) {
            float pj = __shfl(pb, j * 8 + h2);
            acc0 += pj * u2f(vv[8 + j] << 16);
            acc1 += pj * u2f(vv[8 + j] & 0xffff0000u);
        }
    }
    float la = __shfl(l, h2);
    la = fmaxf(la, 1e-12f);
    unsigned o = ((unsigned)(unsigned short)f2bf(acc0 / la)) |
                 (((unsigned)(unsigned short)f2bf(acc1 / la)) << 16);
    *(unsigned*)(aggb + (size_t)n * DM + lane * 2) = o;
}

// ---------------------------------------------------------------------------
// agg@Wo + bo + x -> LN1 -> h (f32) and hb (bf16)
__global__ __launch_bounds__(256) void k_gemm_ln1(
    const short* __restrict__ aggb, const short* __restrict__ Wot,
    const float* __restrict__ bo, const float* __restrict__ x,
    const float* __restrict__ g, const float* __restrict__ b,
    float* __restrict__ h, short* __restrict__ hb)
{
    __shared__ union { short ab[2 * 16384]; float hs[128 * 129]; } u;
    __shared__ float mu[128], rsd[128];
    const int tid = threadIdx.x, lane = tid & 63, wid = tid >> 6;
    const int wm = wid >> 1, wn = wid & 1;
    const int r0 = blockIdx.x * 128;

    stage_tile(aggb, r0, NN - 1, 128, 0, u.ab);
    stage_tile(Wot, 0, 127, 128, 0, u.ab + 16384);
    __syncthreads();

    f32x4 acc[4][4];
    #pragma unroll
    for (int i = 0; i < 4; ++i)
        #pragma unroll
        for (int j = 0; j < 4; ++j) acc[i][j] = (f32x4){0.f, 0.f, 0.f, 0.f};
    mfma_tile(u.ab, u.ab + 16384, wm, wn, lane, acc);
    __syncthreads();

    #pragma unroll
    for (int fn = 0; fn < 4; ++fn) {
        int col = wn * 64 + fn * 16 + (lane & 15);
        float bc = bo[col];
        #pragma unroll
        for (int fm = 0; fm < 4; ++fm) {
            int rowb = wm * 64 + fm * 16 + (lane >> 4) * 4;
            #pragma unroll
            for (int rr = 0; rr < 4; ++rr) {
                int r_ = rowb + rr, gr = r0 + r_;
                float xr = (gr < NN) ? x[(size_t)gr * DM + col] : 0.f;
                u.hs[r_ * 129 + col] = acc[fm][fn][rr] + bc + xr;
            }
        }
    }
    __syncthreads();

    {
        int rrow = tid >> 1, half = tid & 1;
        float s = 0.f, q = 0.f;
        #pragma unroll 8
        for (int c = 0; c < 64; ++c) {
            float v = u.hs[rrow * 129 + half * 64 + c];
            s += v; q += v * v;
        }
        s += __shfl_xor(s, 1);
        q += __shfl_xor(q, 1);
        float m = s * (1.f / DM);
        float var = q * (1.f / DM) - m * m;
        if (half == 0) { mu[rrow] = m; rsd[rrow] = rsqrtf(var + 1e-5f); }
    }
    __syncthreads();

    for (int i = 0; i < 64; ++i) {
        int idx = i * 256 + tid;
        int rrow = idx >> 7, c = idx & 127;
        int gr = r0 + rrow;
        if (gr < NN) {
            float v = (u.hs[rrow * 129 + c] - mu[rrow]) * rsd[rrow] * g[c] + b[c];
            h[(size_t)gr * DM + c] = v;
            hb[(size_t)gr * DM + c] = f2bf(v);
        }
    }
}

// ---------------------------------------------------------------------------
// Fused FFN: gelu(hb@W1+b1)@W2 + b2 + h -> LN2 -> out.  BM=64, 64KB dyn LDS.
__global__ __launch_bounds__(256) void k_ffn_fused(
    const short* __restrict__ hb, const short* __restrict__ Wt1,
    const float* __restrict__ b1, const short* __restrict__ Wt2,
    const float* __restrict__ b2, const float* __restrict__ h,
    const float* __restrict__ g, const float* __restrict__ bb,
    float* __restrict__ out)
{
    extern __shared__ char smraw[];
    short* A = (short*)smraw;          // 16 KB
    short* B = A + 8192;               // 32 KB
    short* C = B + 16384;              // 16 KB
    float* hs = (float*)smraw;         // overlay after gemms
    __shared__ float mu[64], rsd[64];

    const int tid = threadIdx.x, lane = tid & 63, wid = tid >> 6;
    const int wm = wid >> 1, wn = wid & 1;
    const int r0 = blockIdx.x * 64;

    f32x4 acc2[2][4];
    #pragma unroll
    for (int i = 0; i < 2; ++i)
        #pragma unroll
        for (int j = 0; j < 4; ++j) acc2[i][j] = (f32x4){0.f, 0.f, 0.f, 0.f};

    stage_tile64(hb, r0, NN - 1, 128, 0, A);

    for (int kc = 0; kc < 4; ++kc) {
        if (kc) __syncthreads();
        stage_tile(Wt1, kc * 128, FF - 1, 128, 0, B);
        __syncthreads();

        f32x4 accf[2][4];
        #pragma unroll
        for (int i = 0; i < 2; ++i)
            #pragma unroll
            for (int j = 0; j < 4; ++j) accf[i][j] = (f32x4){0.f, 0.f, 0.f, 0.f};
        mfma_tile64(A, B, wm, wn, lane, accf);

        #pragma unroll
        for (int fn = 0; fn < 4; ++fn) {
            int nloc = wn * 64 + fn * 16 + (lane & 15);
            float bc = b1[kc * 128 + nloc];
            int slot = nloc >> 3;
            #pragma unroll
            for (int fm = 0; fm < 2; ++fm) {
                int rowb = wm * 32 + fm * 16 + (lane >> 4) * 4;
                #pragma unroll
                for (int rr = 0; rr < 4; ++rr) {
                    int row = rowb + rr;
                    float v = accf[fm][fn][rr] + bc;
                    v = 0.5f * v * (1.f + erff(v * 0.70710678118654752f));
                    C[row * 128 + (((slot ^ (row & 7)) << 3) | (nloc & 7))] = f2bf(v);
                }
            }
        }
        __syncthreads();
        stage_tile(Wt2, 0, 127, FF, kc * 128, B);
        __syncthreads();
        mfma_tile64(C, B, wm, wn, lane, acc2);
    }
    __syncthreads();

    #pragma unroll
    for (int fn = 0; fn < 4; ++fn) {
        int col = wn * 64 + fn * 16 + (lane & 15);
        float bc = b2[col];
        #pragma unroll
        for (int fm = 0; fm < 2; ++fm) {
            int rowb = wm * 32 + fm * 16 + (lane >> 4) * 4;
            #pragma unroll
            for (int rr = 0; rr < 4; ++rr) {
                int r_ = rowb + rr, gr = r0 + r_;
                float hr = (gr < NN) ? h[(size_t)gr * DM + col] : 0.f;
                hs[r_ * 129 + col] = acc2[fm][fn][rr] + bc + hr;
            }
        }
    }
    __syncthreads();

    {
        int rrow = tid >> 2, q = tid & 3;
        float s = 0.f, qq = 0.f;
        #pragma unroll 8
        for (int c = 0; c < 32; ++c) {
            float v = hs[rrow * 129 + q * 32 + c];
            s += v; qq += v * v;
        }
        s += __shfl_xor(s, 1);  qq += __shfl_xor(qq, 1);
        s += __shfl_xor(s, 2);  qq += __shfl_xor(qq, 2);
        float m = s * (1.f / DM);
        float var = qq * (1.f / DM) - m * m;
        if (q == 0) { mu[rrow] = m; rsd[rrow] = rsqrtf(var + 1e-5f); }
    }
    __syncthreads();

    for (int i = 0; i < 32; ++i) {
        int idx = i * 256 + tid;
        int rrow = idx >> 7, c = idx & 127;
        int gr = r0 + rrow;
        if (gr < NN)
            out[(size_t)gr * DM + c] =
                (hs[rrow * 129 + c] - mu[rrow]) * rsd[rrow] * g[c] + bb[c];
    }
}

// ---------------------------------------------------------------------------
extern "C" void kernel_launch(void* const* d_in, const int* in_sizes, int n_in,
                              void* d_out, int out_size, void* d_ws, size_t ws_size,
                              hipStream_t stream) {
    const float* x   = (const float*)d_in[0];
    const int* row   = (const int*)d_in[1];
    const int* col   = (const int*)d_in[2];
    const int* db    = (const int*)d_in[3];
    const float* Wq  = (const float*)d_in[4];
    const float* bq  = (const float*)d_in[5];
    const float* Wk  = (const float*)d_in[6];
    const float* bk  = (const float*)d_in[7];
    const float* Wv  = (const float*)d_in[8];
    const float* bv  = (const float*)d_in[9];
    const float* Wo  = (const float*)d_in[10];
    const float* bo  = (const float*)d_in[11];
    const float* emb = (const float*)d_in[12];
    const float* g1  = (const float*)d_in[13];
    const float* b1n = (const float*)d_in[14];
    const float* g2  = (const float*)d_in[15];
    const float* b2n = (const float*)d_in[16];
    const float* W1  = (const float*)d_in[17];
    const float* b1  = (const float*)d_in[18];
    const float* W2  = (const float*)d_in[19];
    const float* b2  = (const float*)d_in[20];

    char* W = (char*)d_ws;
    float* embn   = (float*)(W + 0);             // 1.6 MB (free zone)
    short* aggb   = (short*)(W + 25600000);
    short* xb     = (short*)(W + 38400000);
    short* Qb     = (short*)(W + 51200000);
    short* Kb     = (short*)(W + 64000000);
    float* h      = (float*)(W + 51200000);      // overlay (Qb/Kb dead)
    short* Vb     = (short*)(W + 76800000);
    short* hb     = (short*)(W + 76800000);      // overlay (Vb dead)
    short* wts    = (short*)(W + 89600000);
    int* rowptr   = (int*)(W + 89993216);

    k_prep<<<PB_TOT, 256, 0, stream>>>(x, xb, Wq, Wk, Wv, Wo, W1, W2, wts,
                                       row, rowptr, db, emb, embn);
    k_gemm_qkv<<<NBLK, 256, 0, stream>>>(xb, wts, bq, bk, bv, Qb, Kb, Vb);
    k_attn_wave<<<NN / 4, 256, 0, stream>>>(Qb, Kb, Vb, col, rowptr, embn, aggb);
    k_gemm_ln1<<<NBLK, 256, 0, stream>>>(aggb, wts + 49152, bo, x, g1, b1n, h, hb);
    k_ffn_fused<<<NBLK64, 256, 65536, stream>>>(hb, wts + 65536, b1,
                                                wts + 131072, b2, h, g2, b2n,
                                                (float*)d_out);
}